// Round 3
// baseline (6129.387 us; speedup 1.0000x reference)
//
#include <hip/hip_runtime.h>

typedef unsigned int u32;
typedef unsigned short u16;
typedef __attribute__((ext_vector_type(8))) short s8v;   // 8 x bf16 (4 VGPRs)
typedef __attribute__((ext_vector_type(4))) float f4v;   // MFMA accumulator

#define DEV static __device__ __forceinline__

DEV float b2f(u32 u){ return __uint_as_float(u << 16); }
DEV u16 f2bf(float f){ u32 u = __float_as_uint(f); u += 0x7fffu + ((u >> 16) & 1u); return (u16)(u >> 16); }
DEV float dot2(u32 a, u32 b){ return b2f(a & 0xffffu)*b2f(b & 0xffffu) + b2f(a >> 16)*b2f(b >> 16); }
DEV f4v mfma16(s8v a, s8v b, f4v c){ return __builtin_amdgcn_mfma_f32_16x16x32_bf16(a, b, c, 0, 0, 0); }

// ---------------------------------------------------------------------------
// Weight prep: f32 [K][N] -> bf16 MFMA-frag blocks.
// Block b = nt*Ksteps+ks holds 512 bf16: lane ln, elem j <-> W[ks*32+8*(ln>>4)+j][nt*16+(ln&15)]
// ---------------------------------------------------------------------------
__global__ void prep_frag(const float* __restrict__ src, const int Ksteps, const int Nout,
                          u16* __restrict__ dst){
  const int b = blockIdx.x;
  const int ks = b % Ksteps, nt = b / Ksteps;
  const int ln = threadIdx.x;
  const int col = nt*16 + (ln & 15);
  const int kr  = ks*32 + (ln >> 4)*8;
  __align__(16) u16 tmp[8];
#pragma unroll
  for(int j = 0; j < 8; j++) tmp[j] = f2bf(src[(size_t)(kr + j)*Nout + col]);
  *(uint4*)(dst + (size_t)b*512 + ln*8) = *(const uint4*)tmp;
}

// plain transpose for node-head: dst[j][d] = src[d][j], 256x256
__global__ void prep_plainT(const float* __restrict__ src, u16* __restrict__ dst){
  const int j = blockIdx.x, d = threadIdx.x;
  dst[(size_t)j*256 + d] = f2bf(src[(size_t)d*256 + j]);
}

// padding_mask -> bitmask per node, runtime dtype detection (bool8/int32/f32)
__global__ void prep_mask(const unsigned char* __restrict__ pm, u32* __restrict__ mb){
  __shared__ int s0, s3;
  if(threadIdx.x == 0){ s0 = 0; s3 = 0; }
  __syncthreads();
  int a0 = 0, a3 = 0;
  for(int i = threadIdx.x; i < 4096; i += 256){
    unsigned char v = pm[i];
    if(v){ int r = i & 3; if(r == 0) a0 = 1; if(r == 3) a3 = 1; }
  }
  if(a0) s0 = 1;
  if(a3) s3 = 1;
  __syncthreads();
  int mode;                       // 0 = bool8, 1 = int32, 2 = float32
  if(s0 && !s3) mode = 1; else if(!s0 && s3) mode = 2; else mode = 0;
  const int n = blockIdx.x*256 + threadIdx.x;
  u32 bits = 0;
  for(int m = 0; m < 32; m++){
    size_t idx = (size_t)n*32 + m;
    bool v;
    if(mode == 0)      v = pm[idx] != 0;
    else if(mode == 1) v = ((const int*)pm)[idx] != 0;
    else               v = ((const float*)pm)[idx] != 0.f;
    bits |= (v ? 1u : 0u) << m;
  }
  mb[n] = bits;
}

// masked softmax over D-layout scores; stores P (bf16) in-place over q columns
// (stride 264) + col-32 fixup (f32)
DEV void softmax_store(const f4v sS[3][3], u16* Pb, float* a32W,
                       const bool vmask0, const bool vmask1, const bool vmask2,
                       const int lg, const int lr){
  const float sc = 0.17677669529663687f;  // 1/sqrt(32)
#pragma unroll
  for(int rt = 0; rt < 3; rt++){
#pragma unroll
    for(int r = 0; r < 4; r++){
      float sv0 = vmask0 ? sS[rt][0][r]*sc : -1e9f;
      float sv1 = vmask1 ? sS[rt][1][r]*sc : -1e9f;
      float sv2 = vmask2 ? sS[rt][2][r]*sc : -1e9f;
      float m_ = fmaxf(fmaxf(sv0, sv1), sv2);
#pragma unroll
      for(int off = 1; off < 16; off <<= 1) m_ = fmaxf(m_, __shfl_xor(m_, off));
      float e0 = __expf(sv0 - m_), e1 = __expf(sv1 - m_), e2 = __expf(sv2 - m_);
      float sum = e0 + e1 + e2;
#pragma unroll
      for(int off = 1; off < 16; off <<= 1) sum += __shfl_xor(sum, off);
      const float rinv = 1.f/sum;
      const int row = rt*16 + lg*4 + r;
      if(row < 33){
        Pb[row*264 + lr]      = f2bf(e0*rinv);
        Pb[row*264 + 16 + lr] = f2bf(e1*rinv);
        if(lr == 0) a32W[row] = e2*rinv;
      }
    }
  }
}

// ---------------------------------------------------------------------------
// Fused per-layer kernel. block = node (8192), 512 threads = 8 waves, wave = head.
// LDS 54,880 B: tok[33][264] | qb[33][264] (q/P/o/h) | kb[33][264] (x/k/v/y)
//             | a32 8x[33] f32 | ered 8x[48] f32 | nred[4] f32
// ---------------------------------------------------------------------------
__global__ __launch_bounds__(512, 4) void k_layer(
    const int* __restrict__ species, const int* __restrict__ nspec,
    const float* __restrict__ evec, const float* __restrict__ edist,
    const float* __restrict__ cutf, const int* __restrict__ rni,
    const float* __restrict__ emb_nb, const float* __restrict__ emb_nd,
    const float* __restrict__ Wr, const float* __restrict__ br,
    const float* __restrict__ g1, const float* __restrict__ lb1,
    const float* __restrict__ g2, const float* __restrict__ lb2,
    const u16* __restrict__ wqkvf, const u16* __restrict__ wof,
    const u16* __restrict__ w1f, const u16* __restrict__ w2f,
    const float* __restrict__ b1, const float* __restrict__ b2,
    const u16* __restrict__ ehf, const float* __restrict__ ehb,
    const float* __restrict__ efw, const float* __restrict__ efb,
    const u16* __restrict__ nhT, const float* __restrict__ nhb,
    const float* __restrict__ nfw, const float* __restrict__ nfb,
    const u32* __restrict__ maskb, u16* __restrict__ oe,
    const int layer, float* __restrict__ energies)
{
  __shared__ __align__(16) unsigned char sm[54880];
  u16* tok    = (u16*)sm;             // [33][264] bf16 residual stream
  u16* qb     = (u16*)(sm + 17424);   // q -> P -> o -> h
  u16* kb     = (u16*)(sm + 34848);   // x -> k -> v -> y
  float* a32  = (float*)(sm + 52272); // 8 x 33 f32
  float* ered = (float*)(sm + 53328); // 8 x 48 f32
  float* nred = (float*)(sm + 54864); // 4 f32

  const int l = layer;
  const float* emb_ndl = emb_nd + (size_t)l*30464;
  const float* Wrl  = Wr  + l*1024;  const float* brl  = br  + l*256;
  const float* g1l  = g1  + l*256;   const float* lb1l = lb1 + l*256;
  const float* g2l  = g2  + l*256;   const float* lb2l = lb2 + l*256;
  const u16*   wq   = wqkvf + (size_t)l*196608;
  const u16*   wo   = wof + (size_t)l*65536;
  const u16*   w1   = w1f + (size_t)l*262144;
  const u16*   w2   = w2f + (size_t)l*262144;
  const float* b1l  = b1 + l*1024;   const float* b2l  = b2 + l*256;
  const u16*   eh   = ehf + (size_t)l*65536;
  const float* ehbl = ehb + l*256;   const float* efwl = efw + l*256;
  const float  efbv = efb[l];
  const u16*   nh   = nhT + (size_t)l*65536;
  const float* nhbl = nhb + l*256;   const float* nfwl = nfw + l*256;
  const float  nfbv = nfb[l];

  const int n = blockIdx.x, t = threadIdx.x;
  const int w = t >> 6, ln = t & 63, lr = ln & 15, lg = ln >> 4;
  const int d0 = ln*4;
  const f4v zf = {0.f, 0.f, 0.f, 0.f};

  // ===== Phase 1: build tokens -> tok bf16 + LN1 -> kb (x). row = w mod 8
  for(int row = w; row < 33; row += 8){
    float v0, v1, v2, v3;
    if(row == 0){
      const float4 f = *(const float4*)(emb_ndl + (size_t)species[n]*256 + d0);
      v0 = f.x; v1 = f.y; v2 = f.z; v3 = f.w;
    }else{
      const int m = row - 1;
      const size_t em = (size_t)n*32 + m;
      float4 msg = *(const float4*)(emb_nb + (size_t)nspec[em]*256 + d0);
      if(l){
        const uint2 o2 = *(const uint2*)(oe + (size_t)rni[em]*256 + d0);
        msg.x = 0.5f*(msg.x + b2f(o2.x & 0xffffu));
        msg.y = 0.5f*(msg.y + b2f(o2.x >> 16));
        msg.z = 0.5f*(msg.z + b2f(o2.y & 0xffffu));
        msg.w = 0.5f*(msg.w + b2f(o2.y >> 16));
      }
      const float e0 = evec[em*3], e1 = evec[em*3+1], e2 = evec[em*3+2], dd = edist[em];
      const float4 w0 = *(const float4*)(Wrl + d0),        w1v = *(const float4*)(Wrl + 256 + d0);
      const float4 w2v = *(const float4*)(Wrl + 512 + d0), w3  = *(const float4*)(Wrl + 768 + d0);
      const float4 bb = *(const float4*)(brl + d0);
      const float c = cutf[em];
      v0 = (msg.x + e0*w0.x + e1*w1v.x + e2*w2v.x + dd*w3.x + bb.x)*c;
      v1 = (msg.y + e0*w0.y + e1*w1v.y + e2*w2v.y + dd*w3.y + bb.y)*c;
      v2 = (msg.z + e0*w0.z + e1*w1v.z + e2*w2v.z + dd*w3.z + bb.z)*c;
      v3 = (msg.w + e0*w0.w + e1*w1v.w + e2*w2v.w + dd*w3.w + bb.w)*c;
    }
    uint2 tv;
    tv.x = (u32)f2bf(v0) | ((u32)f2bf(v1) << 16);
    tv.y = (u32)f2bf(v2) | ((u32)f2bf(v3) << 16);
    *(uint2*)(tok + row*264 + d0) = tv;
    float s1 = v0+v1+v2+v3, s2 = v0*v0+v1*v1+v2*v2+v3*v3;
#pragma unroll
    for(int off = 1; off < 64; off <<= 1){ s1 += __shfl_xor(s1, off); s2 += __shfl_xor(s2, off); }
    const float mu  = s1*(1.f/256.f);
    const float inv = rsqrtf(s2*(1.f/256.f) - mu*mu + 1e-5f);
    uint2 xo;
    xo.x = (u32)f2bf((v0-mu)*inv*g1l[d0]   + lb1l[d0])   | ((u32)f2bf((v1-mu)*inv*g1l[d0+1] + lb1l[d0+1]) << 16);
    xo.y = (u32)f2bf((v2-mu)*inv*g1l[d0+2] + lb1l[d0+2]) | ((u32)f2bf((v3-mu)*inv*g1l[d0+3] + lb1l[d0+3]) << 16);
    *(uint2*)(kb + row*264 + d0) = xo;
  }
  __syncthreads();

  // ===== Phase 2: A-frag preload (x) from kb
  s8v af[3][8];
#pragma unroll
  for(int rt = 0; rt < 3; rt++){
    int row = rt*16 + lr; row = row > 32 ? 32 : row;
#pragma unroll
    for(int ks = 0; ks < 8; ks++) af[rt][ks] = *(const s8v*)(kb + row*264 + ks*32 + lg*8);
  }
  __syncthreads();   // all x reads done before kb is overwritten with k

  // ===== Phase 3: Q,K tiles (q: ctg 0-15 -> qb, k: 16-31 -> kb), 4 per wave
#pragma unroll 1
  for(int i = 0; i < 4; i++){
    const int ctg = w*4 + i;
    f4v a0 = zf, a1 = zf, a2 = zf;
    const u16* wb = wq + (size_t)ctg*4096 + ln*8;
#pragma unroll
    for(int ks = 0; ks < 8; ks++){
      s8v b = *(const s8v*)(wb + ks*512);
      a0 = mfma16(af[0][ks], b, a0);
      a1 = mfma16(af[1][ks], b, a1);
      a2 = mfma16(af[2][ks], b, a2);
    }
#pragma unroll
    for(int rt = 0; rt < 3; rt++){
      f4v av = rt == 0 ? a0 : (rt == 1 ? a1 : a2);
#pragma unroll
      for(int r = 0; r < 4; r++){
        int row = rt*16 + lg*4 + r;
        if(row > 32) continue;
        u16 bv = f2bf(av[r]);
        if(ctg < 16) qb[row*264 + ctg*16 + lr] = bv;
        else         kb[row*264 + (ctg-16)*16 + lr] = bv;
      }
    }
  }
  __syncthreads();

  // ===== Phase 4: scores + softmax, wave w = head w; P stored over q cols (in-place)
  const u32 mb = maskb[n];
  const int hb = w*32;
  u16* Pb = qb + hb;
  float* a32W = a32 + w*33;
  const bool vmask0 = (lr == 0) || ((mb >> (lr-1)) & 1u);   // cols 0..15
  const bool vmask1 = (mb >> (15+lr)) & 1u;                 // cols 16..31 -> edge 15+lr
  const bool vmask2 = (lr == 0) && ((mb >> 31) & 1u);       // col 32 -> edge 31
  {
    s8v aq[3], bk[3];
#pragma unroll
    for(int rt = 0; rt < 3; rt++){ int row = rt*16 + lr; row = row > 32 ? 32 : row; aq[rt] = *(const s8v*)(qb + row*264 + hb + lg*8); }
#pragma unroll
    for(int ct = 0; ct < 3; ct++){ int tk = ct*16 + lr; tk = tk > 32 ? 32 : tk; bk[ct] = *(const s8v*)(kb + tk*264 + hb + lg*8); }
    f4v sS[3][3];
#pragma unroll
    for(int rt = 0; rt < 3; rt++)
#pragma unroll
      for(int ct = 0; ct < 3; ct++) sS[rt][ct] = mfma16(aq[rt], bk[ct], zf);
    softmax_store(sS, Pb, a32W, vmask0, vmask1, vmask2, lg, lr);
  }
  __syncthreads();   // all K reads done before kb is overwritten with V

  // ===== Phase 5: V tiles -> kb ([33][264] layout), 2 per wave
#pragma unroll 1
  for(int i = 0; i < 2; i++){
    const int vt = w*2 + i;
    f4v a0 = zf, a1 = zf, a2 = zf;
    const u16* wb = wq + (size_t)(32 + vt)*4096 + ln*8;
#pragma unroll
    for(int ks = 0; ks < 8; ks++){
      s8v b = *(const s8v*)(wb + ks*512);
      a0 = mfma16(af[0][ks], b, a0);
      a1 = mfma16(af[1][ks], b, a1);
      a2 = mfma16(af[2][ks], b, a2);
    }
#pragma unroll
    for(int rt = 0; rt < 3; rt++){
      f4v av = rt == 0 ? a0 : (rt == 1 ? a1 : a2);
#pragma unroll
      for(int r = 0; r < 4; r++){
        int row = rt*16 + lg*4 + r;
        if(row > 32) continue;
        kb[row*264 + vt*16 + lr] = f2bf(av[r]);
      }
    }
  }
  __syncthreads();

  // ===== Phase 6: PV. ap = P (consumed to regs), o overwrites P in qb
  {
    s8v ap[3];
#pragma unroll
    for(int rt = 0; rt < 3; rt++){ int row = rt*16 + lr; row = row > 32 ? 32 : row; ap[rt] = *(const s8v*)(qb + row*264 + hb + lg*8); }
#pragma unroll
    for(int c2 = 0; c2 < 2; c2++){
      s8v b;
#pragma unroll
      for(int j = 0; j < 8; j++) b[j] = (short)kb[(lg*8 + j)*264 + hb + c2*16 + lr];
      const float vv = b2f(kb[32*264 + hb + c2*16 + lr]);
#pragma unroll
      for(int rt = 0; rt < 3; rt++){
        f4v o_ = mfma16(ap[rt], b, zf);
#pragma unroll
        for(int r = 0; r < 4; r++){
          int row = rt*16 + lg*4 + r;
          int rc = row > 32 ? 32 : row;
          float ov = o_[r] + a32W[rc]*vv;
          if(row < 33) qb[row*264 + hb + c2*16 + lr] = f2bf(ov);
        }
      }
    }
  }
  __syncthreads();

  // ===== Phase 7: O @ Wo + residual into tok (bf16), 2 ct per wave
#pragma unroll 1
  for(int i = 0; i < 2; i++){
    const int ct = w*2 + i;
    f4v c0 = zf, c1 = zf, c2v = zf;
    const u16* wb = wo + (size_t)ct*4096 + ln*8;
#pragma unroll
    for(int ks = 0; ks < 8; ks++){
      s8v b  = *(const s8v*)(wb + ks*512);
      s8v A0 = *(const s8v*)(qb + lr*264      + ks*32 + lg*8);
      s8v A1 = *(const s8v*)(qb + (16+lr)*264 + ks*32 + lg*8);
      s8v A2 = *(const s8v*)(qb + 32*264      + ks*32 + lg*8);
      c0 = mfma16(A0, b, c0); c1 = mfma16(A1, b, c1); c2v = mfma16(A2, b, c2v);
    }
    const int col = ct*16 + lr;
#pragma unroll
    for(int rt = 0; rt < 3; rt++){
      f4v av = rt == 0 ? c0 : (rt == 1 ? c1 : c2v);
#pragma unroll
      for(int r = 0; r < 4; r++){
        int row = rt*16 + lg*4 + r;
        if(row > 32) continue;
        float tv = b2f(tok[row*264 + col]) + av[r];
        tok[row*264 + col] = f2bf(tv);
      }
    }
  }
  __syncthreads();

  // ===== Phase 8: LN2 -> kb (y)
  for(int row = w; row < 33; row += 8){
    uint2 tv2 = *(const uint2*)(tok + row*264 + d0);
    float v0 = b2f(tv2.x & 0xffffu), v1 = b2f(tv2.x >> 16);
    float v2 = b2f(tv2.y & 0xffffu), v3 = b2f(tv2.y >> 16);
    float s1 = v0+v1+v2+v3, s2 = v0*v0+v1*v1+v2*v2+v3*v3;
#pragma unroll
    for(int off = 1; off < 64; off <<= 1){ s1 += __shfl_xor(s1, off); s2 += __shfl_xor(s2, off); }
    const float mu  = s1*(1.f/256.f);
    const float inv = rsqrtf(s2*(1.f/256.f) - mu*mu + 1e-5f);
    uint2 yo;
    yo.x = (u32)f2bf((v0-mu)*inv*g2l[d0]   + lb2l[d0])   | ((u32)f2bf((v1-mu)*inv*g2l[d0+1] + lb2l[d0+1]) << 16);
    yo.y = (u32)f2bf((v2-mu)*inv*g2l[d0+2] + lb2l[d0+2]) | ((u32)f2bf((v3-mu)*inv*g2l[d0+3] + lb2l[d0+3]) << 16);
    *(uint2*)(kb + row*264 + d0) = yo;
  }
  __syncthreads();

  // ===== Phase 9: FFN. af = y frags; h chunks in qb; facc in regs
#pragma unroll
  for(int rt = 0; rt < 3; rt++){
    int row = rt*16 + lr; row = row > 32 ? 32 : row;
#pragma unroll
    for(int ks = 0; ks < 8; ks++) af[rt][ks] = *(const s8v*)(kb + row*264 + ks*32 + lg*8);
  }
  f4v facc[2][3];
#pragma unroll
  for(int i = 0; i < 2; i++){ facc[i][0] = zf; facc[i][1] = zf; facc[i][2] = zf; }

  for(int ch = 0; ch < 4; ch++){
#pragma unroll 1
    for(int i = 0; i < 2; i++){
      const int nt = ch*16 + w*2 + i;
      f4v h0 = zf, h1 = zf, h2 = zf;
      const u16* wb = w1 + (size_t)nt*4096 + ln*8;
#pragma unroll
      for(int ks = 0; ks < 8; ks++){
        s8v b = *(const s8v*)(wb + ks*512);
        h0 = mfma16(af[0][ks], b, h0);
        h1 = mfma16(af[1][ks], b, h1);
        h2 = mfma16(af[2][ks], b, h2);
      }
      const int colL = (w*2 + i)*16 + lr;
      const float bias = b1l[nt*16 + lr];
#pragma unroll
      for(int rt = 0; rt < 3; rt++){
        f4v hv = rt == 0 ? h0 : (rt == 1 ? h1 : h2);
#pragma unroll
        for(int r = 0; r < 4; r++){
          int row = rt*16 + lg*4 + r;
          if(row > 32) continue;
          float v0 = hv[r] + bias;
          qb[row*264 + colL] = f2bf(v0/(1.f + __expf(-v0)));
        }
      }
    }
    __syncthreads();
#pragma unroll
    for(int i = 0; i < 2; i++){          // fully unrolled: facc indices static
      const int ct = w*2 + i;
      const u16* wb = w2 + ((size_t)ct*32 + ch*8)*512 + ln*8;
#pragma unroll
      for(int ks = 0; ks < 8; ks++){
        s8v b  = *(const s8v*)(wb + ks*512);
        s8v A0 = *(const s8v*)(qb + lr*264      + ks*32 + lg*8);
        s8v A1 = *(const s8v*)(qb + (16+lr)*264 + ks*32 + lg*8);
        s8v A2 = *(const s8v*)(qb + 32*264      + ks*32 + lg*8);
        facc[i][0] = mfma16(A0, b, facc[i][0]);
        facc[i][1] = mfma16(A1, b, facc[i][1]);
        facc[i][2] = mfma16(A2, b, facc[i][2]);
      }
    }
    __syncthreads();
  }

  // ===== Phase 10: final residual -> tok; out_edge (layer 0)
#pragma unroll
  for(int i = 0; i < 2; i++){
    const int ct = w*2 + i, col = ct*16 + lr;
    const float bias2 = b2l[col];
#pragma unroll
    for(int rt = 0; rt < 3; rt++){
#pragma unroll
      for(int r = 0; r < 4; r++){
        int row = rt*16 + lg*4 + r;
        if(row > 32) continue;
        float tv = b2f(tok[row*264 + col]) + facc[i][rt][r] + bias2;
        u16 tvb = f2bf(tv);
        tok[row*264 + col] = tvb;
        if(l == 0 && row > 0) oe[((size_t)n*32 + (row-1))*256 + col] = tvb;
      }
    }
  }
  __syncthreads();

  // ===== Phase 11: heads + energy
  float rp[3][4];
#pragma unroll
  for(int a = 0; a < 3; a++)
#pragma unroll
    for(int r = 0; r < 4; r++) rp[a][r] = 0.f;
#pragma unroll 1
  for(int i = 0; i < 2; i++){
    const int ct = w*2 + i, col = ct*16 + lr;
    f4v e0 = zf, e1 = zf, e2 = zf;
    const u16* wb = eh + (size_t)ct*4096 + ln*8;
#pragma unroll
    for(int ks = 0; ks < 8; ks++){
      s8v b  = *(const s8v*)(wb + ks*512);
      s8v A0 = *(const s8v*)(tok + lr*264      + ks*32 + lg*8);
      s8v A1 = *(const s8v*)(tok + (16+lr)*264 + ks*32 + lg*8);
      s8v A2 = *(const s8v*)(tok + 32*264      + ks*32 + lg*8);
      e0 = mfma16(A0, b, e0); e1 = mfma16(A1, b, e1); e2 = mfma16(A2, b, e2);
    }
    const float bb = ehbl[col], ff = efwl[col];
#pragma unroll
    for(int rt = 0; rt < 3; rt++){
      f4v ev = rt == 0 ? e0 : (rt == 1 ? e1 : e2);
#pragma unroll
      for(int r = 0; r < 4; r++){ float v0 = ev[r] + bb; rp[rt][r] += (v0/(1.f + __expf(-v0)))*ff; }
    }
  }
#pragma unroll
  for(int rt = 0; rt < 3; rt++)
#pragma unroll
    for(int r = 0; r < 4; r++){
      float v = rp[rt][r];
#pragma unroll
      for(int off = 1; off < 16; off <<= 1) v += __shfl_xor(v, off);
      if(lr == 0) ered[w*48 + rt*16 + lg*4 + r] = v;
    }

  if(w < 4){   // node head: thread t (<256) computes hidden[t] from tok row 0
    const u16* nr = nh + (size_t)t*256;
    float acc = 0.f;
#pragma unroll 4
    for(int dd = 0; dd < 256; dd += 8){
      uint4 ta = *(const uint4*)(tok + dd);
      uint4 na = *(const uint4*)(nr + dd);
      acc += dot2(ta.x, na.x) + dot2(ta.y, na.y) + dot2(ta.z, na.z) + dot2(ta.w, na.w);
    }
    float hv = acc + nhbl[t];
    hv = hv/(1.f + __expf(-hv));
    float pp = hv*nfwl[t];
#pragma unroll
    for(int off = 1; off < 64; off <<= 1) pp += __shfl_xor(pp, off);
    if(ln == 0) nred[w] = pp;
  }
  __syncthreads();

  if(w == 0){
    float ev = 0.f;
    if(ln < 32){
      const int row = ln + 1;
      float es = efbv;
#pragma unroll
      for(int ww = 0; ww < 8; ww++) es += ered[ww*48 + row];
      if((mb >> ln) & 1u) ev = es*cutf[(size_t)n*32 + ln];
    }
#pragma unroll
    for(int off = 1; off < 64; off <<= 1) ev += __shfl_xor(ev, off);
    if(ln == 0){
      float tot = ev + nred[0] + nred[1] + nred[2] + nred[3] + nfbv;
      energies[n] = (l ? energies[n] : 0.f) + tot;
    }
  }
}

// ---------------------------------------------------------------------------
extern "C" void kernel_launch(void* const* d_in, const int* in_sizes, int n_in,
                              void* d_out, int out_size, void* d_ws, size_t ws_size,
                              hipStream_t stream){
  (void)in_sizes; (void)n_in; (void)out_size;
  const int*   species = (const int*)d_in[0];
  const int*   nspec   = (const int*)d_in[1];
  const float* evec    = (const float*)d_in[2];
  const float* edist   = (const float*)d_in[3];
  const int*   rni     = (const int*)d_in[5];
  const float* cutf    = (const float*)d_in[6];
  const float* emb_nb  = (const float*)d_in[7];
  const float* emb_nd  = (const float*)d_in[8];
  const float* Wr      = (const float*)d_in[9];
  const float* br      = (const float*)d_in[10];
  const float* Wq      = (const float*)d_in[11];
  const float* Wk      = (const float*)d_in[12];
  const float* Wv      = (const float*)d_in[13];
  const float* Wo      = (const float*)d_in[14];
  const float* W1      = (const float*)d_in[15];
  const float* b1      = (const float*)d_in[16];
  const float* W2      = (const float*)d_in[17];
  const float* b2      = (const float*)d_in[18];
  const float* g1      = (const float*)d_in[19];
  const float* lb1     = (const float*)d_in[20];
  const float* g2      = (const float*)d_in[21];
  const float* lb2     = (const float*)d_in[22];
  const float* nhW     = (const float*)d_in[23];
  const float* nhb     = (const float*)d_in[24];
  const float* nfw     = (const float*)d_in[25];
  const float* nfb     = (const float*)d_in[26];
  const float* ehW     = (const float*)d_in[27];
  const float* ehb     = (const float*)d_in[28];
  const float* efw     = (const float*)d_in[29];
  const float* efb     = (const float*)d_in[30];
  float* energies = (float*)d_out;

  // workspace layout (total 137,920,512 B)
  char* wsb = (char*)d_ws;
  u16* oe     = (u16*)(wsb);                      // 134,217,728 B
  u16* wqkvf  = (u16*)(wsb + 134217728LL);        // 786,432 B
  u16* wof    = (u16*)(wsb + 135004160LL);        // 262,144 B
  u16* w1f    = (u16*)(wsb + 135266304LL);        // 1,048,576 B
  u16* w2f    = (u16*)(wsb + 136314880LL);        // 1,048,576 B
  u16* ehf    = (u16*)(wsb + 137363456LL);        // 262,144 B
  u16* nhT    = (u16*)(wsb + 137625600LL);        // 262,144 B
  u32* maskb  = (u32*)(wsb + 137887744LL);        // 32,768 B
  if(ws_size < 137920512ULL) return;   // undersized ws -> clean absmax failure, not a fault

  for(int l = 0; l < 2; l++){
    const size_t wqo = (size_t)l*196608;
    prep_frag<<<128, 64, 0, stream>>>(Wq + (size_t)l*65536, 8, 256, wqkvf + wqo);
    prep_frag<<<128, 64, 0, stream>>>(Wk + (size_t)l*65536, 8, 256, wqkvf + wqo + 65536);
    prep_frag<<<128, 64, 0, stream>>>(Wv + (size_t)l*65536, 8, 256, wqkvf + wqo + 131072);
    prep_frag<<<128, 64, 0, stream>>>(Wo + (size_t)l*65536, 8, 256, wof + (size_t)l*65536);
    prep_frag<<<512, 64, 0, stream>>>(W1 + (size_t)l*262144, 8, 1024, w1f + (size_t)l*262144);
    prep_frag<<<512, 64, 0, stream>>>(W2 + (size_t)l*262144, 32, 256, w2f + (size_t)l*262144);
    prep_frag<<<128, 64, 0, stream>>>(ehW + (size_t)l*65536, 8, 256, ehf + (size_t)l*65536);
    prep_plainT<<<256, 256, 0, stream>>>(nhW + (size_t)l*65536, nhT + (size_t)l*65536);
  }
  prep_mask<<<32, 256, 0, stream>>>((const unsigned char*)d_in[4], maskb);

  for(int l = 0; l < 2; l++){
    k_layer<<<8192, 512, 0, stream>>>(species, nspec, evec, edist, cutf, rni,
        emb_nb, emb_nd, Wr, br, g1, lb1, g2, lb2,
        wqkvf, wof, w1f, w2f, b1, b2,
        ehf, ehb, efw, efb, nhT, nhb, nfw, nfb,
        maskb, oe, l, energies);
  }
}

// Round 4
// 2873.663 us; speedup vs baseline: 2.1330x; 2.1330x over previous
//
#include <hip/hip_runtime.h>

typedef unsigned int u32;
typedef unsigned short u16;
typedef __attribute__((ext_vector_type(8))) short s8v;   // 8 x bf16 (4 VGPRs)
typedef __attribute__((ext_vector_type(4))) float f4v;   // MFMA accumulator

#define DEV static __device__ __forceinline__

DEV float b2f(u32 u){ return __uint_as_float(u << 16); }
DEV u16 f2bf(float f){ u32 u = __float_as_uint(f); u += 0x7fffu + ((u >> 16) & 1u); return (u16)(u >> 16); }
DEV float dot2(u32 a, u32 b){ return b2f(a & 0xffffu)*b2f(b & 0xffffu) + b2f(a >> 16)*b2f(b >> 16); }
DEV f4v mfma16(s8v a, s8v b, f4v c){ return __builtin_amdgcn_mfma_f32_16x16x32_bf16(a, b, c, 0, 0, 0); }

// ---------------------------------------------------------------------------
// Weight prep: f32 [K][N] -> bf16 MFMA-frag blocks.
// Block b = nt*Ksteps+ks holds 512 bf16: lane ln, elem j <-> W[ks*32+8*(ln>>4)+j][nt*16+(ln&15)]
// ---------------------------------------------------------------------------
__global__ void prep_frag(const float* __restrict__ src, const int Ksteps, const int Nout,
                          u16* __restrict__ dst){
  const int b = blockIdx.x;
  const int ks = b % Ksteps, nt = b / Ksteps;
  const int ln = threadIdx.x;
  const int col = nt*16 + (ln & 15);
  const int kr  = ks*32 + (ln >> 4)*8;
  __align__(16) u16 tmp[8];
#pragma unroll
  for(int j = 0; j < 8; j++) tmp[j] = f2bf(src[(size_t)(kr + j)*Nout + col]);
  *(uint4*)(dst + (size_t)b*512 + ln*8) = *(const uint4*)tmp;
}

// plain transpose for node-head: dst[j][d] = src[d][j], 256x256
__global__ void prep_plainT(const float* __restrict__ src, u16* __restrict__ dst){
  const int j = blockIdx.x, d = threadIdx.x;
  dst[(size_t)j*256 + d] = f2bf(src[(size_t)d*256 + j]);
}

// padding_mask -> bitmask per node, runtime dtype detection (bool8/int32/f32)
__global__ void prep_mask(const unsigned char* __restrict__ pm, u32* __restrict__ mb){
  __shared__ int s0, s3;
  if(threadIdx.x == 0){ s0 = 0; s3 = 0; }
  __syncthreads();
  int a0 = 0, a3 = 0;
  for(int i = threadIdx.x; i < 4096; i += 256){
    unsigned char v = pm[i];
    if(v){ int r = i & 3; if(r == 0) a0 = 1; if(r == 3) a3 = 1; }
  }
  if(a0) s0 = 1;
  if(a3) s3 = 1;
  __syncthreads();
  int mode;                       // 0 = bool8, 1 = int32, 2 = float32
  if(s0 && !s3) mode = 1; else if(!s0 && s3) mode = 2; else mode = 0;
  const int n = blockIdx.x*256 + threadIdx.x;
  u32 bits = 0;
  for(int m = 0; m < 32; m++){
    size_t idx = (size_t)n*32 + m;
    bool v;
    if(mode == 0)      v = pm[idx] != 0;
    else if(mode == 1) v = ((const int*)pm)[idx] != 0;
    else               v = ((const float*)pm)[idx] != 0.f;
    bits |= (v ? 1u : 0u) << m;
  }
  mb[n] = bits;
}

// masked softmax over D-layout scores; stores P (bf16) in-place over q columns
// (stride 264) + col-32 fixup (f32)
DEV void softmax_store(const f4v sS[3][3], u16* Pb, float* a32W,
                       const bool vmask0, const bool vmask1, const bool vmask2,
                       const int lg, const int lr){
  const float sc = 0.17677669529663687f;  // 1/sqrt(32)
#pragma unroll
  for(int rt = 0; rt < 3; rt++){
#pragma unroll
    for(int r = 0; r < 4; r++){
      float sv0 = vmask0 ? sS[rt][0][r]*sc : -1e9f;
      float sv1 = vmask1 ? sS[rt][1][r]*sc : -1e9f;
      float sv2 = vmask2 ? sS[rt][2][r]*sc : -1e9f;
      float m_ = fmaxf(fmaxf(sv0, sv1), sv2);
#pragma unroll
      for(int off = 1; off < 16; off <<= 1) m_ = fmaxf(m_, __shfl_xor(m_, off));
      float e0 = __expf(sv0 - m_), e1 = __expf(sv1 - m_), e2 = __expf(sv2 - m_);
      float sum = e0 + e1 + e2;
#pragma unroll
      for(int off = 1; off < 16; off <<= 1) sum += __shfl_xor(sum, off);
      const float rinv = 1.f/sum;
      const int row = rt*16 + lg*4 + r;
      if(row < 33){
        Pb[row*264 + lr]      = f2bf(e0*rinv);
        Pb[row*264 + 16 + lr] = f2bf(e1*rinv);
        if(lr == 0) a32W[row] = e2*rinv;
      }
    }
  }
}

// ---------------------------------------------------------------------------
// Fused per-layer kernel. block = node (8192), 512 threads = 8 waves, wave = head.
// LDS 55,408 B: tok[33][264] | qb[33][264] (q/P/o/h) | kb[33][264] (x/k/v/y)
//             | a32 8x[33] | ered 8x[48] | nred[4] | xrow32[264]
// Persistent regs: af[2][8] (row-tiles 0,1 only; row 32 broadcast read from LDS).
// ---------------------------------------------------------------------------
__global__ __launch_bounds__(512, 2) void k_layer(
    const int* __restrict__ species, const int* __restrict__ nspec,
    const float* __restrict__ evec, const float* __restrict__ edist,
    const float* __restrict__ cutf, const int* __restrict__ rni,
    const float* __restrict__ emb_nb, const float* __restrict__ emb_nd,
    const float* __restrict__ Wr, const float* __restrict__ br,
    const float* __restrict__ g1, const float* __restrict__ lb1,
    const float* __restrict__ g2, const float* __restrict__ lb2,
    const u16* __restrict__ wqkvf, const u16* __restrict__ wof,
    const u16* __restrict__ w1f, const u16* __restrict__ w2f,
    const float* __restrict__ b1, const float* __restrict__ b2,
    const u16* __restrict__ ehf, const float* __restrict__ ehb,
    const float* __restrict__ efw, const float* __restrict__ efb,
    const u16* __restrict__ nhT, const float* __restrict__ nhb,
    const float* __restrict__ nfw, const float* __restrict__ nfb,
    const u32* __restrict__ maskb, u16* __restrict__ oe,
    const int layer, float* __restrict__ energies)
{
  __shared__ __align__(16) unsigned char sm[55408];
  u16* tok    = (u16*)sm;             // [33][264] bf16 residual stream
  u16* qb     = (u16*)(sm + 17424);   // q -> P -> o -> h
  u16* kb     = (u16*)(sm + 34848);   // x -> k -> v -> y
  float* a32  = (float*)(sm + 52272); // 8 x 33 f32
  float* ered = (float*)(sm + 53328); // 8 x 48 f32
  float* nred = (float*)(sm + 54864); // 4 f32
  u16* xrow32 = (u16*)(sm + 54880);   // 264 bf16: x row 32 stash

  const int l = layer;
  const float* emb_ndl = emb_nd + (size_t)l*30464;
  const float* Wrl  = Wr  + l*1024;  const float* brl  = br  + l*256;
  const float* g1l  = g1  + l*256;   const float* lb1l = lb1 + l*256;
  const float* g2l  = g2  + l*256;   const float* lb2l = lb2 + l*256;
  const u16*   wq   = wqkvf + (size_t)l*196608;
  const u16*   wo   = wof + (size_t)l*65536;
  const u16*   w1   = w1f + (size_t)l*262144;
  const u16*   w2   = w2f + (size_t)l*262144;
  const float* b1l  = b1 + l*1024;   const float* b2l  = b2 + l*256;
  const u16*   eh   = ehf + (size_t)l*65536;
  const float* ehbl = ehb + l*256;   const float* efwl = efw + l*256;
  const float  efbv = efb[l];
  const u16*   nh   = nhT + (size_t)l*65536;
  const float* nhbl = nhb + l*256;   const float* nfwl = nfw + l*256;
  const float  nfbv = nfb[l];

  const int n = blockIdx.x, t = threadIdx.x;
  const int w = t >> 6, ln = t & 63, lr = ln & 15, lg = ln >> 4;
  const int d0 = ln*4;
  const f4v zf = {0.f, 0.f, 0.f, 0.f};

  // ===== Phase 1: build tokens -> tok bf16 + LN1 -> kb (x) [+ xrow32 stash]
  for(int row = w; row < 33; row += 8){
    float v0, v1, v2, v3;
    if(row == 0){
      const float4 f = *(const float4*)(emb_ndl + (size_t)species[n]*256 + d0);
      v0 = f.x; v1 = f.y; v2 = f.z; v3 = f.w;
    }else{
      const int m = row - 1;
      const size_t em = (size_t)n*32 + m;
      float4 msg = *(const float4*)(emb_nb + (size_t)nspec[em]*256 + d0);
      if(l){
        const uint2 o2 = *(const uint2*)(oe + (size_t)rni[em]*256 + d0);
        msg.x = 0.5f*(msg.x + b2f(o2.x & 0xffffu));
        msg.y = 0.5f*(msg.y + b2f(o2.x >> 16));
        msg.z = 0.5f*(msg.z + b2f(o2.y & 0xffffu));
        msg.w = 0.5f*(msg.w + b2f(o2.y >> 16));
      }
      const float e0 = evec[em*3], e1 = evec[em*3+1], e2 = evec[em*3+2], dd = edist[em];
      const float4 w0 = *(const float4*)(Wrl + d0),        w1v = *(const float4*)(Wrl + 256 + d0);
      const float4 w2v = *(const float4*)(Wrl + 512 + d0), w3  = *(const float4*)(Wrl + 768 + d0);
      const float4 bb = *(const float4*)(brl + d0);
      const float c = cutf[em];
      v0 = (msg.x + e0*w0.x + e1*w1v.x + e2*w2v.x + dd*w3.x + bb.x)*c;
      v1 = (msg.y + e0*w0.y + e1*w1v.y + e2*w2v.y + dd*w3.y + bb.y)*c;
      v2 = (msg.z + e0*w0.z + e1*w1v.z + e2*w2v.z + dd*w3.z + bb.z)*c;
      v3 = (msg.w + e0*w0.w + e1*w1v.w + e2*w2v.w + dd*w3.w + bb.w)*c;
    }
    uint2 tv;
    tv.x = (u32)f2bf(v0) | ((u32)f2bf(v1) << 16);
    tv.y = (u32)f2bf(v2) | ((u32)f2bf(v3) << 16);
    *(uint2*)(tok + row*264 + d0) = tv;
    float s1 = v0+v1+v2+v3, s2 = v0*v0+v1*v1+v2*v2+v3*v3;
#pragma unroll
    for(int off = 1; off < 64; off <<= 1){ s1 += __shfl_xor(s1, off); s2 += __shfl_xor(s2, off); }
    const float mu  = s1*(1.f/256.f);
    const float inv = rsqrtf(s2*(1.f/256.f) - mu*mu + 1e-5f);
    uint2 xo;
    xo.x = (u32)f2bf((v0-mu)*inv*g1l[d0]   + lb1l[d0])   | ((u32)f2bf((v1-mu)*inv*g1l[d0+1] + lb1l[d0+1]) << 16);
    xo.y = (u32)f2bf((v2-mu)*inv*g1l[d0+2] + lb1l[d0+2]) | ((u32)f2bf((v3-mu)*inv*g1l[d0+3] + lb1l[d0+3]) << 16);
    *(uint2*)(kb + row*264 + d0) = xo;
    if(row == 32) *(uint2*)(xrow32 + d0) = xo;
  }
  __syncthreads();

  // ===== Phase 2: A-frag preload (x rows 0..31) from kb
  s8v af[2][8];
#pragma unroll
  for(int rt = 0; rt < 2; rt++){
    const int row = rt*16 + lr;
#pragma unroll
    for(int ks = 0; ks < 8; ks++) af[rt][ks] = *(const s8v*)(kb + row*264 + ks*32 + lg*8);
  }
  __syncthreads();   // all x reads done before kb is overwritten with k

  // ===== Phase 3: Q,K tiles (q: ctg 0-15 -> qb, k: 16-31 -> kb), 4 per wave
#pragma unroll 1
  for(int i = 0; i < 4; i++){
    const int ctg = w*4 + i;
    f4v a0 = zf, a1 = zf, a2 = zf;
    const u16* wb = wq + (size_t)ctg*4096 + ln*8;
#pragma unroll
    for(int ks = 0; ks < 8; ks++){
      s8v b = *(const s8v*)(wb + ks*512);
      s8v a2k = *(const s8v*)(xrow32 + ks*32 + lg*8);   // broadcast row 32
      a0 = mfma16(af[0][ks], b, a0);
      a1 = mfma16(af[1][ks], b, a1);
      a2 = mfma16(a2k, b, a2);
    }
#pragma unroll
    for(int rt = 0; rt < 3; rt++){
      f4v av = rt == 0 ? a0 : (rt == 1 ? a1 : a2);
#pragma unroll
      for(int r = 0; r < 4; r++){
        int row = rt*16 + lg*4 + r;
        if(row > 32) continue;
        u16 bv = f2bf(av[r]);
        if(ctg < 16) qb[row*264 + ctg*16 + lr] = bv;
        else         kb[row*264 + (ctg-16)*16 + lr] = bv;
      }
    }
  }
  __syncthreads();

  // ===== Phase 4: scores + softmax, wave w = head w; P stored over q cols (in-place)
  const u32 mb = maskb[n];
  const int hb = w*32;
  u16* Pb = qb + hb;
  float* a32W = a32 + w*33;
  const bool vmask0 = (lr == 0) || ((mb >> (lr-1)) & 1u);   // cols 0..15
  const bool vmask1 = (mb >> (15+lr)) & 1u;                 // cols 16..31 -> edge 15+lr
  const bool vmask2 = (lr == 0) && ((mb >> 31) & 1u);       // col 32 -> edge 31
  {
    s8v aq[3], bk[3];
#pragma unroll
    for(int rt = 0; rt < 3; rt++){ int row = rt*16 + lr; row = row > 32 ? 32 : row; aq[rt] = *(const s8v*)(qb + row*264 + hb + lg*8); }
#pragma unroll
    for(int ct = 0; ct < 3; ct++){ int tk = ct*16 + lr; tk = tk > 32 ? 32 : tk; bk[ct] = *(const s8v*)(kb + tk*264 + hb + lg*8); }
    f4v sS[3][3];
#pragma unroll
    for(int rt = 0; rt < 3; rt++)
#pragma unroll
      for(int ct = 0; ct < 3; ct++) sS[rt][ct] = mfma16(aq[rt], bk[ct], zf);
    softmax_store(sS, Pb, a32W, vmask0, vmask1, vmask2, lg, lr);
  }
  __syncthreads();   // all K reads done before kb is overwritten with V

  // ===== Phase 5: V tiles -> kb ([33][264] layout), 2 per wave
#pragma unroll 1
  for(int i = 0; i < 2; i++){
    const int vt = w*2 + i;
    f4v a0 = zf, a1 = zf, a2 = zf;
    const u16* wb = wq + (size_t)(32 + vt)*4096 + ln*8;
#pragma unroll
    for(int ks = 0; ks < 8; ks++){
      s8v b = *(const s8v*)(wb + ks*512);
      s8v a2k = *(const s8v*)(xrow32 + ks*32 + lg*8);   // broadcast row 32
      a0 = mfma16(af[0][ks], b, a0);
      a1 = mfma16(af[1][ks], b, a1);
      a2 = mfma16(a2k, b, a2);
    }
#pragma unroll
    for(int rt = 0; rt < 3; rt++){
      f4v av = rt == 0 ? a0 : (rt == 1 ? a1 : a2);
#pragma unroll
      for(int r = 0; r < 4; r++){
        int row = rt*16 + lg*4 + r;
        if(row > 32) continue;
        kb[row*264 + vt*16 + lr] = f2bf(av[r]);
      }
    }
  }
  __syncthreads();

  // ===== Phase 6: PV. ap = P (consumed to regs), o overwrites P in qb
  {
    s8v ap[3];
#pragma unroll
    for(int rt = 0; rt < 3; rt++){ int row = rt*16 + lr; row = row > 32 ? 32 : row; ap[rt] = *(const s8v*)(qb + row*264 + hb + lg*8); }
#pragma unroll
    for(int c2 = 0; c2 < 2; c2++){
      s8v b;
#pragma unroll
      for(int j = 0; j < 8; j++) b[j] = (short)kb[(lg*8 + j)*264 + hb + c2*16 + lr];
      const float vv = b2f(kb[32*264 + hb + c2*16 + lr]);
#pragma unroll
      for(int rt = 0; rt < 3; rt++){
        f4v o_ = mfma16(ap[rt], b, zf);
#pragma unroll
        for(int r = 0; r < 4; r++){
          int row = rt*16 + lg*4 + r;
          int rc = row > 32 ? 32 : row;
          float ov = o_[r] + a32W[rc]*vv;
          if(row < 33) qb[row*264 + hb + c2*16 + lr] = f2bf(ov);
        }
      }
    }
  }
  __syncthreads();

  // ===== Phase 7: O @ Wo + residual into tok (bf16), 2 ct per wave
#pragma unroll 1
  for(int i = 0; i < 2; i++){
    const int ct = w*2 + i;
    f4v c0 = zf, c1 = zf, c2v = zf;
    const u16* wb = wo + (size_t)ct*4096 + ln*8;
#pragma unroll
    for(int ks = 0; ks < 8; ks++){
      s8v b  = *(const s8v*)(wb + ks*512);
      s8v A0 = *(const s8v*)(qb + lr*264      + ks*32 + lg*8);
      s8v A1 = *(const s8v*)(qb + (16+lr)*264 + ks*32 + lg*8);
      s8v A2 = *(const s8v*)(qb + 32*264      + ks*32 + lg*8);
      c0 = mfma16(A0, b, c0); c1 = mfma16(A1, b, c1); c2v = mfma16(A2, b, c2v);
    }
    const int col = ct*16 + lr;
#pragma unroll
    for(int rt = 0; rt < 3; rt++){
      f4v av = rt == 0 ? c0 : (rt == 1 ? c1 : c2v);
#pragma unroll
      for(int r = 0; r < 4; r++){
        int row = rt*16 + lg*4 + r;
        if(row > 32) continue;
        float tv = b2f(tok[row*264 + col]) + av[r];
        tok[row*264 + col] = f2bf(tv);
      }
    }
  }
  __syncthreads();

  // ===== Phase 8: LN2 -> kb (y)
  for(int row = w; row < 33; row += 8){
    uint2 tv2 = *(const uint2*)(tok + row*264 + d0);
    float v0 = b2f(tv2.x & 0xffffu), v1 = b2f(tv2.x >> 16);
    float v2 = b2f(tv2.y & 0xffffu), v3 = b2f(tv2.y >> 16);
    float s1 = v0+v1+v2+v3, s2 = v0*v0+v1*v1+v2*v2+v3*v3;
#pragma unroll
    for(int off = 1; off < 64; off <<= 1){ s1 += __shfl_xor(s1, off); s2 += __shfl_xor(s2, off); }
    const float mu  = s1*(1.f/256.f);
    const float inv = rsqrtf(s2*(1.f/256.f) - mu*mu + 1e-5f);
    uint2 yo;
    yo.x = (u32)f2bf((v0-mu)*inv*g2l[d0]   + lb2l[d0])   | ((u32)f2bf((v1-mu)*inv*g2l[d0+1] + lb2l[d0+1]) << 16);
    yo.y = (u32)f2bf((v2-mu)*inv*g2l[d0+2] + lb2l[d0+2]) | ((u32)f2bf((v3-mu)*inv*g2l[d0+3] + lb2l[d0+3]) << 16);
    *(uint2*)(kb + row*264 + d0) = yo;
  }
  __syncthreads();

  // ===== Phase 9: FFN. af = y frags (rows 0..31); row 32 read inline from kb
#pragma unroll
  for(int rt = 0; rt < 2; rt++){
    const int row = rt*16 + lr;
#pragma unroll
    for(int ks = 0; ks < 8; ks++) af[rt][ks] = *(const s8v*)(kb + row*264 + ks*32 + lg*8);
  }
  f4v facc[2][3];
#pragma unroll
  for(int i = 0; i < 2; i++){ facc[i][0] = zf; facc[i][1] = zf; facc[i][2] = zf; }

  for(int ch = 0; ch < 4; ch++){
#pragma unroll 1
    for(int i = 0; i < 2; i++){
      const int nt = ch*16 + w*2 + i;
      f4v h0 = zf, h1 = zf, h2 = zf;
      const u16* wb = w1 + (size_t)nt*4096 + ln*8;
#pragma unroll
      for(int ks = 0; ks < 8; ks++){
        s8v b = *(const s8v*)(wb + ks*512);
        s8v a2k = *(const s8v*)(kb + 32*264 + ks*32 + lg*8);  // y row 32 (kb intact)
        h0 = mfma16(af[0][ks], b, h0);
        h1 = mfma16(af[1][ks], b, h1);
        h2 = mfma16(a2k, b, h2);
      }
      const int colL = (w*2 + i)*16 + lr;
      const float bias = b1l[nt*16 + lr];
#pragma unroll
      for(int rt = 0; rt < 3; rt++){
        f4v hv = rt == 0 ? h0 : (rt == 1 ? h1 : h2);
#pragma unroll
        for(int r = 0; r < 4; r++){
          int row = rt*16 + lg*4 + r;
          if(row > 32) continue;
          float v0 = hv[r] + bias;
          qb[row*264 + colL] = f2bf(v0/(1.f + __expf(-v0)));
        }
      }
    }
    __syncthreads();
#pragma unroll
    for(int i = 0; i < 2; i++){          // fully unrolled: facc indices static
      const int ct = w*2 + i;
      const u16* wb = w2 + ((size_t)ct*32 + ch*8)*512 + ln*8;
#pragma unroll
      for(int ks = 0; ks < 8; ks++){
        s8v b  = *(const s8v*)(wb + ks*512);
        s8v A0 = *(const s8v*)(qb + lr*264      + ks*32 + lg*8);
        s8v A1 = *(const s8v*)(qb + (16+lr)*264 + ks*32 + lg*8);
        s8v A2 = *(const s8v*)(qb + 32*264      + ks*32 + lg*8);
        facc[i][0] = mfma16(A0, b, facc[i][0]);
        facc[i][1] = mfma16(A1, b, facc[i][1]);
        facc[i][2] = mfma16(A2, b, facc[i][2]);
      }
    }
    __syncthreads();
  }

  // ===== Phase 10: final residual -> tok; out_edge (layer 0)
#pragma unroll
  for(int i = 0; i < 2; i++){
    const int ct = w*2 + i, col = ct*16 + lr;
    const float bias2 = b2l[col];
#pragma unroll
    for(int rt = 0; rt < 3; rt++){
#pragma unroll
      for(int r = 0; r < 4; r++){
        int row = rt*16 + lg*4 + r;
        if(row > 32) continue;
        float tv = b2f(tok[row*264 + col]) + facc[i][rt][r] + bias2;
        u16 tvb = f2bf(tv);
        tok[row*264 + col] = tvb;
        if(l == 0 && row > 0) oe[((size_t)n*32 + (row-1))*256 + col] = tvb;
      }
    }
  }
  __syncthreads();

  // ===== Phase 11: heads + energy
  float rp[3][4];
#pragma unroll
  for(int a = 0; a < 3; a++)
#pragma unroll
    for(int r = 0; r < 4; r++) rp[a][r] = 0.f;
#pragma unroll 1
  for(int i = 0; i < 2; i++){
    const int ct = w*2 + i, col = ct*16 + lr;
    f4v e0 = zf, e1 = zf, e2 = zf;
    const u16* wb = eh + (size_t)ct*4096 + ln*8;
#pragma unroll
    for(int ks = 0; ks < 8; ks++){
      s8v b  = *(const s8v*)(wb + ks*512);
      s8v A0 = *(const s8v*)(tok + lr*264      + ks*32 + lg*8);
      s8v A1 = *(const s8v*)(tok + (16+lr)*264 + ks*32 + lg*8);
      s8v A2 = *(const s8v*)(tok + 32*264      + ks*32 + lg*8);
      e0 = mfma16(A0, b, e0); e1 = mfma16(A1, b, e1); e2 = mfma16(A2, b, e2);
    }
    const float bb = ehbl[col], ff = efwl[col];
#pragma unroll
    for(int rt = 0; rt < 3; rt++){
      f4v ev = rt == 0 ? e0 : (rt == 1 ? e1 : e2);
#pragma unroll
      for(int r = 0; r < 4; r++){ float v0 = ev[r] + bb; rp[rt][r] += (v0/(1.f + __expf(-v0)))*ff; }
    }
  }
#pragma unroll
  for(int rt = 0; rt < 3; rt++)
#pragma unroll
    for(int r = 0; r < 4; r++){
      float v = rp[rt][r];
#pragma unroll
      for(int off = 1; off < 16; off <<= 1) v += __shfl_xor(v, off);
      if(lr == 0) ered[w*48 + rt*16 + lg*4 + r] = v;
    }

  if(w < 4){   // node head: thread t (<256) computes hidden[t] from tok row 0
    const u16* nr = nh + (size_t)t*256;
    float acc = 0.f;
#pragma unroll 4
    for(int dd = 0; dd < 256; dd += 8){
      uint4 ta = *(const uint4*)(tok + dd);
      uint4 na = *(const uint4*)(nr + dd);
      acc += dot2(ta.x, na.x) + dot2(ta.y, na.y) + dot2(ta.z, na.z) + dot2(ta.w, na.w);
    }
    float hv = acc + nhbl[t];
    hv = hv/(1.f + __expf(-hv));
    float pp = hv*nfwl[t];
#pragma unroll
    for(int off = 1; off < 64; off <<= 1) pp += __shfl_xor(pp, off);
    if(ln == 0) nred[w] = pp;
  }
  __syncthreads();

  if(w == 0){
    float ev = 0.f;
    if(ln < 32){
      const int row = ln + 1;
      float es = efbv;
#pragma unroll
      for(int ww = 0; ww < 8; ww++) es += ered[ww*48 + row];
      if((mb >> ln) & 1u) ev = es*cutf[(size_t)n*32 + ln];
    }
#pragma unroll
    for(int off = 1; off < 64; off <<= 1) ev += __shfl_xor(ev, off);
    if(ln == 0){
      float tot = ev + nred[0] + nred[1] + nred[2] + nred[3] + nfbv;
      energies[n] = (l ? energies[n] : 0.f) + tot;
    }
  }
}

// ---------------------------------------------------------------------------
extern "C" void kernel_launch(void* const* d_in, const int* in_sizes, int n_in,
                              void* d_out, int out_size, void* d_ws, size_t ws_size,
                              hipStream_t stream){
  (void)in_sizes; (void)n_in; (void)out_size;
  const int*   species = (const int*)d_in[0];
  const int*   nspec   = (const int*)d_in[1];
  const float* evec    = (const float*)d_in[2];
  const float* edist   = (const float*)d_in[3];
  const int*   rni     = (const int*)d_in[5];
  const float* cutf    = (const float*)d_in[6];
  const float* emb_nb  = (const float*)d_in[7];
  const float* emb_nd  = (const float*)d_in[8];
  const float* Wr      = (const float*)d_in[9];
  const float* br      = (const float*)d_in[10];
  const float* Wq      = (const float*)d_in[11];
  const float* Wk      = (const float*)d_in[12];
  const float* Wv      = (const float*)d_in[13];
  const float* Wo      = (const float*)d_in[14];
  const float* W1      = (const float*)d_in[15];
  const float* b1      = (const float*)d_in[16];
  const float* W2      = (const float*)d_in[17];
  const float* b2      = (const float*)d_in[18];
  const float* g1      = (const float*)d_in[19];
  const float* lb1     = (const float*)d_in[20];
  const float* g2      = (const float*)d_in[21];
  const float* lb2     = (const float*)d_in[22];
  const float* nhW     = (const float*)d_in[23];
  const float* nhb     = (const float*)d_in[24];
  const float* nfw     = (const float*)d_in[25];
  const float* nfb     = (const float*)d_in[26];
  const float* ehW     = (const float*)d_in[27];
  const float* ehb     = (const float*)d_in[28];
  const float* efw     = (const float*)d_in[29];
  const float* efb     = (const float*)d_in[30];
  float* energies = (float*)d_out;

  // workspace layout (total 137,920,512 B)
  char* wsb = (char*)d_ws;
  u16* oe     = (u16*)(wsb);                      // 134,217,728 B
  u16* wqkvf  = (u16*)(wsb + 134217728LL);        // 786,432 B
  u16* wof    = (u16*)(wsb + 135004160LL);        // 262,144 B
  u16* w1f    = (u16*)(wsb + 135266304LL);        // 1,048,576 B
  u16* w2f    = (u16*)(wsb + 136314880LL);        // 1,048,576 B
  u16* ehf    = (u16*)(wsb + 137363456LL);        // 262,144 B
  u16* nhT    = (u16*)(wsb + 137625600LL);        // 262,144 B
  u32* maskb  = (u32*)(wsb + 137887744LL);        // 32,768 B
  if(ws_size < 137920512ULL) return;   // undersized ws -> clean absmax failure, not a fault

  for(int l = 0; l < 2; l++){
    const size_t wqo = (size_t)l*196608;
    prep_frag<<<128, 64, 0, stream>>>(Wq + (size_t)l*65536, 8, 256, wqkvf + wqo);
    prep_frag<<<128, 64, 0, stream>>>(Wk + (size_t)l*65536, 8, 256, wqkvf + wqo + 65536);
    prep_frag<<<128, 64, 0, stream>>>(Wv + (size_t)l*65536, 8, 256, wqkvf + wqo + 131072);
    prep_frag<<<128, 64, 0, stream>>>(Wo + (size_t)l*65536, 8, 256, wof + (size_t)l*65536);
    prep_frag<<<512, 64, 0, stream>>>(W1 + (size_t)l*262144, 8, 1024, w1f + (size_t)l*262144);
    prep_frag<<<512, 64, 0, stream>>>(W2 + (size_t)l*262144, 32, 256, w2f + (size_t)l*262144);
    prep_frag<<<128, 64, 0, stream>>>(ehW + (size_t)l*65536, 8, 256, ehf + (size_t)l*65536);
    prep_plainT<<<256, 256, 0, stream>>>(nhW + (size_t)l*65536, nhT + (size_t)l*65536);
  }
  prep_mask<<<32, 256, 0, stream>>>((const unsigned char*)d_in[4], maskb);

  for(int l = 0; l < 2; l++){
    k_layer<<<8192, 512, 0, stream>>>(species, nspec, evec, edist, cutf, rni,
        emb_nb, emb_nd, Wr, br, g1, lb1, g2, lb2,
        wqkvf, wof, w1f, w2f, b1, b2,
        ehf, ehb, efw, efb, nhT, nhb, nfw, nfb,
        maskb, oe, l, energies);
  }
}

// Round 5
// 2563.193 us; speedup vs baseline: 2.3913x; 1.1211x over previous
//
#include <hip/hip_runtime.h>

typedef unsigned int u32;
typedef unsigned short u16;
typedef __attribute__((ext_vector_type(8))) short s8v;   // 8 x bf16 (4 VGPRs)
typedef __attribute__((ext_vector_type(4))) float f4v;   // MFMA accumulator

#define DEV static __device__ __forceinline__

DEV float b2f(u32 u){ return __uint_as_float(u << 16); }
DEV u16 f2bf(float f){ u32 u = __float_as_uint(f); u += 0x7fffu + ((u >> 16) & 1u); return (u16)(u >> 16); }
DEV u32 cvtpk(float lo, float hi){ u32 r; asm("v_cvt_pk_bf16_f32 %0, %1, %2" : "=v"(r) : "v"(lo), "v"(hi)); return r; }
DEV float dot2(u32 a, u32 b){ return b2f(a & 0xffffu)*b2f(b & 0xffffu) + b2f(a >> 16)*b2f(b >> 16); }
DEV f4v mfma16(s8v a, s8v b, f4v c){ return __builtin_amdgcn_mfma_f32_16x16x32_bf16(a, b, c, 0, 0, 0); }

// ---------------------------------------------------------------------------
// Weight prep: f32 [K][N] -> bf16 MFMA-frag blocks.
// Block b = nt*Ksteps+ks holds 512 bf16: lane ln, elem j <-> W[ks*32+8*(ln>>4)+j][nt*16+(ln&15)]
// ---------------------------------------------------------------------------
__global__ void prep_frag(const float* __restrict__ src, const int Ksteps, const int Nout,
                          u16* __restrict__ dst){
  const int b = blockIdx.x;
  const int ks = b % Ksteps, nt = b / Ksteps;
  const int ln = threadIdx.x;
  const int col = nt*16 + (ln & 15);
  const int kr  = ks*32 + (ln >> 4)*8;
  __align__(16) u16 tmp[8];
#pragma unroll
  for(int j = 0; j < 8; j++) tmp[j] = f2bf(src[(size_t)(kr + j)*Nout + col]);
  *(uint4*)(dst + (size_t)b*512 + ln*8) = *(const uint4*)tmp;
}

// plain transpose for node-head: dst[j][d] = src[d][j], 256x256
__global__ void prep_plainT(const float* __restrict__ src, u16* __restrict__ dst){
  const int j = blockIdx.x, d = threadIdx.x;
  dst[(size_t)j*256 + d] = f2bf(src[(size_t)d*256 + j]);
}

// padding_mask -> bitmask per node, runtime dtype detection (bool8/int32/f32)
__global__ void prep_mask(const unsigned char* __restrict__ pm, u32* __restrict__ mb){
  __shared__ int s0, s3;
  if(threadIdx.x == 0){ s0 = 0; s3 = 0; }
  __syncthreads();
  int a0 = 0, a3 = 0;
  for(int i = threadIdx.x; i < 4096; i += 256){
    unsigned char v = pm[i];
    if(v){ int r = i & 3; if(r == 0) a0 = 1; if(r == 3) a3 = 1; }
  }
  if(a0) s0 = 1;
  if(a3) s3 = 1;
  __syncthreads();
  int mode;                       // 0 = bool8, 1 = int32, 2 = float32
  if(s0 && !s3) mode = 1; else if(!s0 && s3) mode = 2; else mode = 0;
  const int n = blockIdx.x*256 + threadIdx.x;
  u32 bits = 0;
  for(int m = 0; m < 32; m++){
    size_t idx = (size_t)n*32 + m;
    bool v;
    if(mode == 0)      v = pm[idx] != 0;
    else if(mode == 1) v = ((const int*)pm)[idx] != 0;
    else               v = ((const float*)pm)[idx] != 0.f;
    bits |= (v ? 1u : 0u) << m;
  }
  mb[n] = bits;
}

// masked softmax over D-layout scores; stores P (bf16) in-place over q columns
// (stride 264) + col-32 fixup (f32)
DEV void softmax_store(const f4v sS[3][3], u16* Pb, float* a32W,
                       const bool vmask0, const bool vmask1, const bool vmask2,
                       const int lg, const int lr){
  const float sc = 0.17677669529663687f;  // 1/sqrt(32)
#pragma unroll
  for(int rt = 0; rt < 3; rt++){
#pragma unroll
    for(int r = 0; r < 4; r++){
      float sv0 = vmask0 ? sS[rt][0][r]*sc : -1e9f;
      float sv1 = vmask1 ? sS[rt][1][r]*sc : -1e9f;
      float sv2 = vmask2 ? sS[rt][2][r]*sc : -1e9f;
      float m_ = fmaxf(fmaxf(sv0, sv1), sv2);
#pragma unroll
      for(int off = 1; off < 16; off <<= 1) m_ = fmaxf(m_, __shfl_xor(m_, off));
      float e0 = __expf(sv0 - m_), e1 = __expf(sv1 - m_), e2 = __expf(sv2 - m_);
      float sum = e0 + e1 + e2;
#pragma unroll
      for(int off = 1; off < 16; off <<= 1) sum += __shfl_xor(sum, off);
      const float rinv = 1.f/sum;
      const int row = rt*16 + lg*4 + r;
      if(row < 33){
        Pb[row*264 + lr]      = f2bf(e0*rinv);
        Pb[row*264 + 16 + lr] = f2bf(e1*rinv);
        if(lr == 0) a32W[row] = e2*rinv;
      }
    }
  }
}

// ---------------------------------------------------------------------------
// Fused per-layer kernel. block = node (8192), 512 threads = 8 waves, wave = head.
// LDS 71,248 B: tok[33][264] | qb (q/P/o/h) | kb (k/v) | xb (x/y)
//             | a32 8x[33] (aliased by ered/nred post-attention)
// No persistent A-frag registers: all MFMA A-operands read inline from LDS.
// ---------------------------------------------------------------------------
__global__ __launch_bounds__(512, 4) void k_layer(
    const int* __restrict__ species, const int* __restrict__ nspec,
    const float* __restrict__ evec, const float* __restrict__ edist,
    const float* __restrict__ cutf, const int* __restrict__ rni,
    const float* __restrict__ emb_nb, const float* __restrict__ emb_nd,
    const float* __restrict__ Wr, const float* __restrict__ br,
    const float* __restrict__ g1, const float* __restrict__ lb1,
    const float* __restrict__ g2, const float* __restrict__ lb2,
    const u16* __restrict__ wqkvf, const u16* __restrict__ wof,
    const u16* __restrict__ w1f, const u16* __restrict__ w2f,
    const float* __restrict__ b1, const float* __restrict__ b2,
    const u16* __restrict__ ehf, const float* __restrict__ ehb,
    const float* __restrict__ efw, const float* __restrict__ efb,
    const u16* __restrict__ nhT, const float* __restrict__ nhb,
    const float* __restrict__ nfw, const float* __restrict__ nfb,
    const u32* __restrict__ maskb, u16* __restrict__ oe,
    const int layer, float* __restrict__ energies)
{
  __shared__ __align__(16) unsigned char sm[71248];
  u16* tok    = (u16*)sm;             // [33][264] bf16 residual stream
  u16* qb     = (u16*)(sm + 17424);   // q -> P -> o -> h
  u16* kb     = (u16*)(sm + 34848);   // k -> v
  u16* xb     = (u16*)(sm + 52272);   // x -> y
  float* a32  = (float*)(sm + 69696); // 8 x 33 f32
  float* ered = (float*)(sm + 69696); // alias a32 (a32 dead after PV)
  float* nred = (float*)(sm + 71232); // 4 f32

  const int l = layer;
  const float* emb_ndl = emb_nd + (size_t)l*30464;
  const float* Wrl  = Wr  + l*1024;  const float* brl  = br  + l*256;
  const float* g1l  = g1  + l*256;   const float* lb1l = lb1 + l*256;
  const float* g2l  = g2  + l*256;   const float* lb2l = lb2 + l*256;
  const u16*   wq   = wqkvf + (size_t)l*196608;
  const u16*   wo   = wof + (size_t)l*65536;
  const u16*   w1   = w1f + (size_t)l*262144;
  const u16*   w2   = w2f + (size_t)l*262144;
  const float* b1l  = b1 + l*1024;   const float* b2l  = b2 + l*256;
  const u16*   eh   = ehf + (size_t)l*65536;
  const float* ehbl = ehb + l*256;   const float* efwl = efw + l*256;
  const float  efbv = efb[l];
  const u16*   nh   = nhT + (size_t)l*65536;
  const float* nhbl = nhb + l*256;   const float* nfwl = nfw + l*256;
  const float  nfbv = nfb[l];

  const int n = blockIdx.x, t = threadIdx.x;
  const int w = t >> 6, ln = t & 63, lr = ln & 15, lg = ln >> 4;
  const int d0 = ln*4;
  const f4v zf = {0.f, 0.f, 0.f, 0.f};

  // A-operand LDS read bases (bf16 elements)
  const int a0off = lr*264      + lg*8;
  const int a1off = (16+lr)*264 + lg*8;
  const int a2off = 32*264      + lg*8;

  // ===== Phase 1: build tokens -> tok bf16 + LN1 -> xb (x)
  for(int row = w; row < 33; row += 8){
    float v0, v1, v2, v3;
    if(row == 0){
      const float4 f = *(const float4*)(emb_ndl + (size_t)species[n]*256 + d0);
      v0 = f.x; v1 = f.y; v2 = f.z; v3 = f.w;
    }else{
      const int m = row - 1;
      const size_t em = (size_t)n*32 + m;
      float4 msg = *(const float4*)(emb_nb + (size_t)nspec[em]*256 + d0);
      if(l){
        const uint2 o2 = *(const uint2*)(oe + (size_t)rni[em]*256 + d0);
        msg.x = 0.5f*(msg.x + b2f(o2.x & 0xffffu));
        msg.y = 0.5f*(msg.y + b2f(o2.x >> 16));
        msg.z = 0.5f*(msg.z + b2f(o2.y & 0xffffu));
        msg.w = 0.5f*(msg.w + b2f(o2.y >> 16));
      }
      const float e0 = evec[em*3], e1 = evec[em*3+1], e2 = evec[em*3+2], dd = edist[em];
      const float4 w0 = *(const float4*)(Wrl + d0),        w1v = *(const float4*)(Wrl + 256 + d0);
      const float4 w2v = *(const float4*)(Wrl + 512 + d0), w3  = *(const float4*)(Wrl + 768 + d0);
      const float4 bb = *(const float4*)(brl + d0);
      const float c = cutf[em];
      v0 = (msg.x + e0*w0.x + e1*w1v.x + e2*w2v.x + dd*w3.x + bb.x)*c;
      v1 = (msg.y + e0*w0.y + e1*w1v.y + e2*w2v.y + dd*w3.y + bb.y)*c;
      v2 = (msg.z + e0*w0.z + e1*w1v.z + e2*w2v.z + dd*w3.z + bb.z)*c;
      v3 = (msg.w + e0*w0.w + e1*w1v.w + e2*w2v.w + dd*w3.w + bb.w)*c;
    }
    uint2 tv; tv.x = cvtpk(v0, v1); tv.y = cvtpk(v2, v3);
    *(uint2*)(tok + row*264 + d0) = tv;
    float s1 = v0+v1+v2+v3, s2 = v0*v0+v1*v1+v2*v2+v3*v3;
#pragma unroll
    for(int off = 1; off < 64; off <<= 1){ s1 += __shfl_xor(s1, off); s2 += __shfl_xor(s2, off); }
    const float mu  = s1*(1.f/256.f);
    const float inv = rsqrtf(s2*(1.f/256.f) - mu*mu + 1e-5f);
    uint2 xo;
    xo.x = cvtpk((v0-mu)*inv*g1l[d0]   + lb1l[d0],   (v1-mu)*inv*g1l[d0+1] + lb1l[d0+1]);
    xo.y = cvtpk((v2-mu)*inv*g1l[d0+2] + lb1l[d0+2], (v3-mu)*inv*g1l[d0+3] + lb1l[d0+3]);
    *(uint2*)(xb + row*264 + d0) = xo;
  }
  __syncthreads();

  // ===== Phase 3: Q,K tiles (q: ctg 0-15 -> qb, k: 16-31 -> kb), 4 per wave
#pragma unroll 1
  for(int i = 0; i < 4; i++){
    const int ctg = w*4 + i;
    const u16* wb = wq + (size_t)ctg*4096 + ln*8;
    s8v bfr[8];
#pragma unroll
    for(int ks = 0; ks < 8; ks++) bfr[ks] = *(const s8v*)(wb + ks*512);
    f4v a0 = zf, a1 = zf, a2 = zf;
#pragma unroll
    for(int ks = 0; ks < 8; ks++){
      s8v x0 = *(const s8v*)(xb + a0off + ks*32);
      s8v x1 = *(const s8v*)(xb + a1off + ks*32);
      s8v x2 = *(const s8v*)(xb + a2off + ks*32);
      a0 = mfma16(x0, bfr[ks], a0);
      a1 = mfma16(x1, bfr[ks], a1);
      a2 = mfma16(x2, bfr[ks], a2);
    }
#pragma unroll
    for(int rt = 0; rt < 3; rt++){
      f4v av = rt == 0 ? a0 : (rt == 1 ? a1 : a2);
#pragma unroll
      for(int r = 0; r < 4; r++){
        int row = rt*16 + lg*4 + r;
        if(row > 32) continue;
        u16 bv = f2bf(av[r]);
        if(ctg < 16) qb[row*264 + ctg*16 + lr] = bv;
        else         kb[row*264 + (ctg-16)*16 + lr] = bv;
      }
    }
  }
  __syncthreads();

  // ===== Phase 4: scores + softmax, wave w = head w; P stored over q cols (in-place)
  const u32 mb = maskb[n];
  const int hb = w*32;
  u16* Pb = qb + hb;
  float* a32W = a32 + w*33;
  const bool vmask0 = (lr == 0) || ((mb >> (lr-1)) & 1u);   // cols 0..15
  const bool vmask1 = (mb >> (15+lr)) & 1u;                 // cols 16..31 -> edge 15+lr
  const bool vmask2 = (lr == 0) && ((mb >> 31) & 1u);       // col 32 -> edge 31
  {
    s8v aq[3], bk[3];
#pragma unroll
    for(int rt = 0; rt < 3; rt++){ int row = rt*16 + lr; row = row > 32 ? 32 : row; aq[rt] = *(const s8v*)(qb + row*264 + hb + lg*8); }
#pragma unroll
    for(int ct = 0; ct < 3; ct++){ int tk = ct*16 + lr; tk = tk > 32 ? 32 : tk; bk[ct] = *(const s8v*)(kb + tk*264 + hb + lg*8); }
    f4v sS[3][3];
#pragma unroll
    for(int rt = 0; rt < 3; rt++)
#pragma unroll
      for(int ct = 0; ct < 3; ct++) sS[rt][ct] = mfma16(aq[rt], bk[ct], zf);
    softmax_store(sS, Pb, a32W, vmask0, vmask1, vmask2, lg, lr);
  }
  __syncthreads();   // all K reads done before kb is overwritten with V

  // ===== Phase 5: V tiles -> kb ([33][264] layout), 2 per wave
#pragma unroll 1
  for(int i = 0; i < 2; i++){
    const int vt = w*2 + i;
    const u16* wb = wq + (size_t)(32 + vt)*4096 + ln*8;
    s8v bfr[8];
#pragma unroll
    for(int ks = 0; ks < 8; ks++) bfr[ks] = *(const s8v*)(wb + ks*512);
    f4v a0 = zf, a1 = zf, a2 = zf;
#pragma unroll
    for(int ks = 0; ks < 8; ks++){
      s8v x0 = *(const s8v*)(xb + a0off + ks*32);
      s8v x1 = *(const s8v*)(xb + a1off + ks*32);
      s8v x2 = *(const s8v*)(xb + a2off + ks*32);
      a0 = mfma16(x0, bfr[ks], a0);
      a1 = mfma16(x1, bfr[ks], a1);
      a2 = mfma16(x2, bfr[ks], a2);
    }
#pragma unroll
    for(int rt = 0; rt < 3; rt++){
      f4v av = rt == 0 ? a0 : (rt == 1 ? a1 : a2);
#pragma unroll
      for(int r = 0; r < 4; r++){
        int row = rt*16 + lg*4 + r;
        if(row > 32) continue;
        kb[row*264 + vt*16 + lr] = f2bf(av[r]);
      }
    }
  }
  __syncthreads();

  // ===== Phase 6: PV. ap = P (consumed to regs), o overwrites P in qb
  {
    s8v ap[3];
#pragma unroll
    for(int rt = 0; rt < 3; rt++){ int row = rt*16 + lr; row = row > 32 ? 32 : row; ap[rt] = *(const s8v*)(qb + row*264 + hb + lg*8); }
#pragma unroll
    for(int c2 = 0; c2 < 2; c2++){
      s8v b;
#pragma unroll
      for(int j = 0; j < 8; j++) b[j] = (short)kb[(lg*8 + j)*264 + hb + c2*16 + lr];
      const float vv = b2f(kb[32*264 + hb + c2*16 + lr]);
#pragma unroll
      for(int rt = 0; rt < 3; rt++){
        f4v o_ = mfma16(ap[rt], b, zf);
#pragma unroll
        for(int r = 0; r < 4; r++){
          int row = rt*16 + lg*4 + r;
          int rc = row > 32 ? 32 : row;
          float ov = o_[r] + a32W[rc]*vv;
          if(row < 33) qb[row*264 + hb + c2*16 + lr] = f2bf(ov);
        }
      }
    }
  }
  __syncthreads();

  // ===== Phase 7: O @ Wo + residual into tok (bf16), 2 ct per wave
#pragma unroll 1
  for(int i = 0; i < 2; i++){
    const int ct = w*2 + i;
    const u16* wb = wo + (size_t)ct*4096 + ln*8;
    s8v bfr[8];
#pragma unroll
    for(int ks = 0; ks < 8; ks++) bfr[ks] = *(const s8v*)(wb + ks*512);
    f4v c0 = zf, c1 = zf, c2v = zf;
#pragma unroll
    for(int ks = 0; ks < 8; ks++){
      s8v A0 = *(const s8v*)(qb + a0off + ks*32);
      s8v A1 = *(const s8v*)(qb + a1off + ks*32);
      s8v A2 = *(const s8v*)(qb + a2off + ks*32);
      c0 = mfma16(A0, bfr[ks], c0); c1 = mfma16(A1, bfr[ks], c1); c2v = mfma16(A2, bfr[ks], c2v);
    }
    const int col = ct*16 + lr;
#pragma unroll
    for(int rt = 0; rt < 3; rt++){
      f4v av = rt == 0 ? c0 : (rt == 1 ? c1 : c2v);
#pragma unroll
      for(int r = 0; r < 4; r++){
        int row = rt*16 + lg*4 + r;
        if(row > 32) continue;
        float tv = b2f(tok[row*264 + col]) + av[r];
        tok[row*264 + col] = f2bf(tv);
      }
    }
  }
  __syncthreads();

  // ===== Phase 8: LN2 -> xb (y)
  for(int row = w; row < 33; row += 8){
    uint2 tv2 = *(const uint2*)(tok + row*264 + d0);
    float v0 = b2f(tv2.x & 0xffffu), v1 = b2f(tv2.x >> 16);
    float v2 = b2f(tv2.y & 0xffffu), v3 = b2f(tv2.y >> 16);
    float s1 = v0+v1+v2+v3, s2 = v0*v0+v1*v1+v2*v2+v3*v3;
#pragma unroll
    for(int off = 1; off < 64; off <<= 1){ s1 += __shfl_xor(s1, off); s2 += __shfl_xor(s2, off); }
    const float mu  = s1*(1.f/256.f);
    const float inv = rsqrtf(s2*(1.f/256.f) - mu*mu + 1e-5f);
    uint2 yo;
    yo.x = cvtpk((v0-mu)*inv*g2l[d0]   + lb2l[d0],   (v1-mu)*inv*g2l[d0+1] + lb2l[d0+1]);
    yo.y = cvtpk((v2-mu)*inv*g2l[d0+2] + lb2l[d0+2], (v3-mu)*inv*g2l[d0+3] + lb2l[d0+3]);
    *(uint2*)(xb + row*264 + d0) = yo;
  }
  __syncthreads();

  // ===== Phase 9: FFN. A (y) read inline from xb; h chunks in qb; facc in regs
  f4v facc[2][3];
#pragma unroll
  for(int i = 0; i < 2; i++){ facc[i][0] = zf; facc[i][1] = zf; facc[i][2] = zf; }

  for(int ch = 0; ch < 4; ch++){
#pragma unroll 1
    for(int i = 0; i < 2; i++){
      const int nt = ch*16 + w*2 + i;
      const u16* wb = w1 + (size_t)nt*4096 + ln*8;
      s8v bfr[8];
#pragma unroll
      for(int ks = 0; ks < 8; ks++) bfr[ks] = *(const s8v*)(wb + ks*512);
      f4v h0 = zf, h1 = zf, h2 = zf;
#pragma unroll
      for(int ks = 0; ks < 8; ks++){
        s8v y0 = *(const s8v*)(xb + a0off + ks*32);
        s8v y1 = *(const s8v*)(xb + a1off + ks*32);
        s8v y2 = *(const s8v*)(xb + a2off + ks*32);
        h0 = mfma16(y0, bfr[ks], h0);
        h1 = mfma16(y1, bfr[ks], h1);
        h2 = mfma16(y2, bfr[ks], h2);
      }
      const int colL = (w*2 + i)*16 + lr;
      const float bias = b1l[nt*16 + lr];
#pragma unroll
      for(int rt = 0; rt < 3; rt++){
        f4v hv = rt == 0 ? h0 : (rt == 1 ? h1 : h2);
#pragma unroll
        for(int r = 0; r < 4; r++){
          int row = rt*16 + lg*4 + r;
          if(row > 32) continue;
          float v0 = hv[r] + bias;
          qb[row*264 + colL] = f2bf(v0/(1.f + __expf(-v0)));
        }
      }
    }
    __syncthreads();
#pragma unroll
    for(int i = 0; i < 2; i++){          // fully unrolled: facc indices static
      const int ct = w*2 + i;
      const u16* wb = w2 + ((size_t)ct*32 + ch*8)*512 + ln*8;
#pragma unroll
      for(int ks = 0; ks < 8; ks++){
        s8v b  = *(const s8v*)(wb + ks*512);
        s8v A0 = *(const s8v*)(qb + a0off + ks*32);
        s8v A1 = *(const s8v*)(qb + a1off + ks*32);
        s8v A2 = *(const s8v*)(qb + a2off + ks*32);
        facc[i][0] = mfma16(A0, b, facc[i][0]);
        facc[i][1] = mfma16(A1, b, facc[i][1]);
        facc[i][2] = mfma16(A2, b, facc[i][2]);
      }
    }
    __syncthreads();
  }

  // ===== Phase 10: final residual -> tok; out_edge (layer 0)
#pragma unroll
  for(int i = 0; i < 2; i++){
    const int ct = w*2 + i, col = ct*16 + lr;
    const float bias2 = b2l[col];
#pragma unroll
    for(int rt = 0; rt < 3; rt++){
#pragma unroll
      for(int r = 0; r < 4; r++){
        int row = rt*16 + lg*4 + r;
        if(row > 32) continue;
        float tv = b2f(tok[row*264 + col]) + facc[i][rt][r] + bias2;
        u16 tvb = f2bf(tv);
        tok[row*264 + col] = tvb;
        if(l == 0 && row > 0) oe[((size_t)n*32 + (row-1))*256 + col] = tvb;
      }
    }
  }
  __syncthreads();

  // ===== Phase 11: heads + energy
  float rp[3][4];
#pragma unroll
  for(int a = 0; a < 3; a++)
#pragma unroll
    for(int r = 0; r < 4; r++) rp[a][r] = 0.f;
#pragma unroll 1
  for(int i = 0; i < 2; i++){
    const int ct = w*2 + i, col = ct*16 + lr;
    const u16* wb = eh + (size_t)ct*4096 + ln*8;
    s8v bfr[8];
#pragma unroll
    for(int ks = 0; ks < 8; ks++) bfr[ks] = *(const s8v*)(wb + ks*512);
    f4v e0 = zf, e1 = zf, e2 = zf;
#pragma unroll
    for(int ks = 0; ks < 8; ks++){
      s8v A0 = *(const s8v*)(tok + a0off + ks*32);
      s8v A1 = *(const s8v*)(tok + a1off + ks*32);
      s8v A2 = *(const s8v*)(tok + a2off + ks*32);
      e0 = mfma16(A0, bfr[ks], e0); e1 = mfma16(A1, bfr[ks], e1); e2 = mfma16(A2, bfr[ks], e2);
    }
    const float bb = ehbl[col], ff = efwl[col];
#pragma unroll
    for(int rt = 0; rt < 3; rt++){
      f4v ev = rt == 0 ? e0 : (rt == 1 ? e1 : e2);
#pragma unroll
      for(int r = 0; r < 4; r++){ float v0 = ev[r] + bb; rp[rt][r] += (v0/(1.f + __expf(-v0)))*ff; }
    }
  }
#pragma unroll
  for(int rt = 0; rt < 3; rt++)
#pragma unroll
    for(int r = 0; r < 4; r++){
      float v = rp[rt][r];
#pragma unroll
      for(int off = 1; off < 16; off <<= 1) v += __shfl_xor(v, off);
      if(lr == 0) ered[w*48 + rt*16 + lg*4 + r] = v;
    }

  if(w < 4){   // node head: thread t (<256) computes hidden[t] from tok row 0
    const u16* nr = nh + (size_t)t*256;
    float acc = 0.f;
#pragma unroll 4
    for(int dd = 0; dd < 256; dd += 8){
      uint4 ta = *(const uint4*)(tok + dd);
      uint4 na = *(const uint4*)(nr + dd);
      acc += dot2(ta.x, na.x) + dot2(ta.y, na.y) + dot2(ta.z, na.z) + dot2(ta.w, na.w);
    }
    float hv = acc + nhbl[t];
    hv = hv/(1.f + __expf(-hv));
    float pp = hv*nfwl[t];
#pragma unroll
    for(int off = 1; off < 64; off <<= 1) pp += __shfl_xor(pp, off);
    if(ln == 0) nred[w] = pp;
  }
  __syncthreads();

  if(w == 0){
    float ev = 0.f;
    if(ln < 32){
      const int row = ln + 1;
      float es = efbv;
#pragma unroll
      for(int ww = 0; ww < 8; ww++) es += ered[ww*48 + row];
      if((mb >> ln) & 1u) ev = es*cutf[(size_t)n*32 + ln];
    }
#pragma unroll
    for(int off = 1; off < 64; off <<= 1) ev += __shfl_xor(ev, off);
    if(ln == 0){
      float tot = ev + nred[0] + nred[1] + nred[2] + nred[3] + nfbv;
      energies[n] = (l ? energies[n] : 0.f) + tot;
    }
  }
}

// ---------------------------------------------------------------------------
extern "C" void kernel_launch(void* const* d_in, const int* in_sizes, int n_in,
                              void* d_out, int out_size, void* d_ws, size_t ws_size,
                              hipStream_t stream){
  (void)in_sizes; (void)n_in; (void)out_size;
  const int*   species = (const int*)d_in[0];
  const int*   nspec   = (const int*)d_in[1];
  const float* evec    = (const float*)d_in[2];
  const float* edist   = (const float*)d_in[3];
  const int*   rni     = (const int*)d_in[5];
  const float* cutf    = (const float*)d_in[6];
  const float* emb_nb  = (const float*)d_in[7];
  const float* emb_nd  = (const float*)d_in[8];
  const float* Wr      = (const float*)d_in[9];
  const float* br      = (const float*)d_in[10];
  const float* Wq      = (const float*)d_in[11];
  const float* Wk      = (const float*)d_in[12];
  const float* Wv      = (const float*)d_in[13];
  const float* Wo      = (const float*)d_in[14];
  const float* W1      = (const float*)d_in[15];
  const float* b1      = (const float*)d_in[16];
  const float* W2      = (const float*)d_in[17];
  const float* b2      = (const float*)d_in[18];
  const float* g1      = (const float*)d_in[19];
  const float* lb1     = (const float*)d_in[20];
  const float* g2      = (const float*)d_in[21];
  const float* lb2     = (const float*)d_in[22];
  const float* nhW     = (const float*)d_in[23];
  const float* nhb     = (const float*)d_in[24];
  const float* nfw     = (const float*)d_in[25];
  const float* nfb     = (const float*)d_in[26];
  const float* ehW     = (const float*)d_in[27];
  const float* ehb     = (const float*)d_in[28];
  const float* efw     = (const float*)d_in[29];
  const float* efb     = (const float*)d_in[30];
  float* energies = (float*)d_out;

  // workspace layout (total 137,920,512 B)
  char* wsb = (char*)d_ws;
  u16* oe     = (u16*)(wsb);                      // 134,217,728 B
  u16* wqkvf  = (u16*)(wsb + 134217728LL);        // 786,432 B
  u16* wof    = (u16*)(wsb + 135004160LL);        // 262,144 B
  u16* w1f    = (u16*)(wsb + 135266304LL);        // 1,048,576 B
  u16* w2f    = (u16*)(wsb + 136314880LL);        // 1,048,576 B
  u16* ehf    = (u16*)(wsb + 137363456LL);        // 262,144 B
  u16* nhT    = (u16*)(wsb + 137625600LL);        // 262,144 B
  u32* maskb  = (u32*)(wsb + 137887744LL);        // 32,768 B
  if(ws_size < 137920512ULL) return;   // undersized ws -> clean absmax failure, not a fault

  for(int l = 0; l < 2; l++){
    const size_t wqo = (size_t)l*196608;
    prep_frag<<<128, 64, 0, stream>>>(Wq + (size_t)l*65536, 8, 256, wqkvf + wqo);
    prep_frag<<<128, 64, 0, stream>>>(Wk + (size_t)l*65536, 8, 256, wqkvf + wqo + 65536);
    prep_frag<<<128, 64, 0, stream>>>(Wv + (size_t)l*65536, 8, 256, wqkvf + wqo + 131072);
    prep_frag<<<128, 64, 0, stream>>>(Wo + (size_t)l*65536, 8, 256, wof + (size_t)l*65536);
    prep_frag<<<512, 64, 0, stream>>>(W1 + (size_t)l*262144, 8, 1024, w1f + (size_t)l*262144);
    prep_frag<<<512, 64, 0, stream>>>(W2 + (size_t)l*262144, 32, 256, w2f + (size_t)l*262144);
    prep_frag<<<128, 64, 0, stream>>>(ehW + (size_t)l*65536, 8, 256, ehf + (size_t)l*65536);
    prep_plainT<<<256, 256, 0, stream>>>(nhW + (size_t)l*65536, nhT + (size_t)l*65536);
  }
  prep_mask<<<32, 256, 0, stream>>>((const unsigned char*)d_in[4], maskb);

  for(int l = 0; l < 2; l++){
    k_layer<<<8192, 512, 0, stream>>>(species, nspec, evec, edist, cutf, rni,
        emb_nb, emb_nd, Wr, br, g1, lb1, g2, lb2,
        wqkvf, wof, w1f, w2f, b1, b2,
        ehf, ehb, efw, efb, nhT, nhb, nfw, nfb,
        maskb, oe, l, energies);
  }
}

// Round 8
// 2033.518 us; speedup vs baseline: 3.0142x; 1.2605x over previous
//
#include <hip/hip_runtime.h>

typedef unsigned int u32;
typedef unsigned short u16;
typedef __attribute__((ext_vector_type(8))) short s8v;   // 8 x bf16 (4 VGPRs)
typedef __attribute__((ext_vector_type(4))) float f4v;   // MFMA accumulator

#define DEV static __device__ __forceinline__

DEV float b2f(u32 u){ return __uint_as_float(u << 16); }
DEV u16 f2bf(float f){ u32 u = __float_as_uint(f); u += 0x7fffu + ((u >> 16) & 1u); return (u16)(u >> 16); }
DEV u32 cvtpk(float lo, float hi){ u32 r; asm("v_cvt_pk_bf16_f32 %0, %1, %2" : "=v"(r) : "v"(lo), "v"(hi)); return r; }
DEV float dot2(u32 a, u32 b){ return b2f(a & 0xffffu)*b2f(b & 0xffffu) + b2f(a >> 16)*b2f(b >> 16); }
DEV f4v mfma16(s8v a, s8v b, f4v c){ return __builtin_amdgcn_mfma_f32_16x16x32_bf16(a, b, c, 0, 0, 0); }

// ---------------------------------------------------------------------------
// Weight prep: f32 [K][N] -> bf16 MFMA-frag blocks.
// Block b = nt*Ksteps+ks holds 512 bf16: lane ln, elem j <-> W[ks*32+8*(ln>>4)+j][nt*16+(ln&15)]
// ---------------------------------------------------------------------------
__global__ void prep_frag(const float* __restrict__ src, const int Ksteps, const int Nout,
                          u16* __restrict__ dst){
  const int b = blockIdx.x;
  const int ks = b % Ksteps, nt = b / Ksteps;
  const int ln = threadIdx.x;
  const int col = nt*16 + (ln & 15);
  const int kr  = ks*32 + (ln >> 4)*8;
  __align__(16) u16 tmp[8];
#pragma unroll
  for(int j = 0; j < 8; j++) tmp[j] = f2bf(src[(size_t)(kr + j)*Nout + col]);
  *(uint4*)(dst + (size_t)b*512 + ln*8) = *(const uint4*)tmp;
}

// plain transpose for node-head: dst[j][d] = src[d][j], 256x256
__global__ void prep_plainT(const float* __restrict__ src, u16* __restrict__ dst){
  const int j = blockIdx.x, d = threadIdx.x;
  dst[(size_t)j*256 + d] = f2bf(src[(size_t)d*256 + j]);
}

// padding_mask -> bitmask per node, runtime dtype detection (bool8/int32/f32)
__global__ void prep_mask(const unsigned char* __restrict__ pm, u32* __restrict__ mb){
  __shared__ int s0, s3;
  if(threadIdx.x == 0){ s0 = 0; s3 = 0; }
  __syncthreads();
  int a0 = 0, a3 = 0;
  for(int i = threadIdx.x; i < 4096; i += 256){
    unsigned char v = pm[i];
    if(v){ int r = i & 3; if(r == 0) a0 = 1; if(r == 3) a3 = 1; }
  }
  if(a0) s0 = 1;
  if(a3) s3 = 1;
  __syncthreads();
  int mode;                       // 0 = bool8, 1 = int32, 2 = float32
  if(s0 && !s3) mode = 1; else if(!s0 && s3) mode = 2; else mode = 0;
  const int n = blockIdx.x*256 + threadIdx.x;
  u32 bits = 0;
  for(int m = 0; m < 32; m++){
    size_t idx = (size_t)n*32 + m;
    bool v;
    if(mode == 0)      v = pm[idx] != 0;
    else if(mode == 1) v = ((const int*)pm)[idx] != 0;
    else               v = ((const float*)pm)[idx] != 0.f;
    bits |= (v ? 1u : 0u) << m;
  }
  mb[n] = bits;
}

// masked softmax over D-layout scores; stores P (bf16) in-place over q columns
// (stride 264) + col-32 fixup (f32)
DEV void softmax_store(const f4v sS[3][3], u16* Pb, float* a32W,
                       const bool vmask0, const bool vmask1, const bool vmask2,
                       const int lg, const int lr){
  const float sc = 0.17677669529663687f;  // 1/sqrt(32)
#pragma unroll
  for(int rt = 0; rt < 3; rt++){
#pragma unroll
    for(int r = 0; r < 4; r++){
      float sv0 = vmask0 ? sS[rt][0][r]*sc : -1e9f;
      float sv1 = vmask1 ? sS[rt][1][r]*sc : -1e9f;
      float sv2 = vmask2 ? sS[rt][2][r]*sc : -1e9f;
      float m_ = fmaxf(fmaxf(sv0, sv1), sv2);
#pragma unroll
      for(int off = 1; off < 16; off <<= 1) m_ = fmaxf(m_, __shfl_xor(m_, off));
      float e0 = __expf(sv0 - m_), e1 = __expf(sv1 - m_), e2 = __expf(sv2 - m_);
      float sum = e0 + e1 + e2;
#pragma unroll
      for(int off = 1; off < 16; off <<= 1) sum += __shfl_xor(sum, off);
      const float rinv = 1.f/sum;
      const int row = rt*16 + lg*4 + r;
      if(row < 33){
        Pb[row*264 + lr]      = f2bf(e0*rinv);
        Pb[row*264 + 16 + lr] = f2bf(e1*rinv);
        if(lr == 0) a32W[row] = e2*rinv;
      }
    }
  }
}

// ---------------------------------------------------------------------------
// Fused per-layer kernel. block = node (8192), 512 threads = 8 waves, wave = head.
// LDS 71,248 B: tok[33][264] | qb (q/P/o/h) | kb (k/v) | xb (x/y)
//             | a32 8x[33] (aliased by ered/nred post-attention)
// GEMM phases are ks-outer: 3 A-frags loaded once per ks, reused by all of the
// wave's col-tiles; per-tile f4v accumulators persist over ks (static indexing).
// Stores are round-5-identical (per-element, guarded).
// ---------------------------------------------------------------------------
__global__ __launch_bounds__(512, 4) void k_layer(
    const int* __restrict__ species, const int* __restrict__ nspec,
    const float* __restrict__ evec, const float* __restrict__ edist,
    const float* __restrict__ cutf, const int* __restrict__ rni,
    const float* __restrict__ emb_nb, const float* __restrict__ emb_nd,
    const float* __restrict__ Wr, const float* __restrict__ br,
    const float* __restrict__ g1, const float* __restrict__ lb1,
    const float* __restrict__ g2, const float* __restrict__ lb2,
    const u16* __restrict__ wqkvf, const u16* __restrict__ wof,
    const u16* __restrict__ w1f, const u16* __restrict__ w2f,
    const float* __restrict__ b1, const float* __restrict__ b2,
    const u16* __restrict__ ehf, const float* __restrict__ ehb,
    const float* __restrict__ efw, const float* __restrict__ efb,
    const u16* __restrict__ nhT, const float* __restrict__ nhb,
    const float* __restrict__ nfw, const float* __restrict__ nfb,
    const u32* __restrict__ maskb, u16* __restrict__ oe,
    const int layer, float* __restrict__ energies)
{
  __shared__ __align__(16) unsigned char sm[71248];
  u16* tok    = (u16*)sm;             // [33][264] bf16 residual stream
  u16* qb     = (u16*)(sm + 17424);   // q -> P -> o -> h
  u16* kb     = (u16*)(sm + 34848);   // k -> v
  u16* xb     = (u16*)(sm + 52272);   // x -> y
  float* a32  = (float*)(sm + 69696); // 8 x 33 f32
  float* ered = (float*)(sm + 69696); // alias a32 (a32 dead after PV)
  float* nred = (float*)(sm + 71232); // 4 f32

  const int l = layer;
  const float* emb_ndl = emb_nd + (size_t)l*30464;
  const float* Wrl  = Wr  + l*1024;  const float* brl  = br  + l*256;
  const float* g1l  = g1  + l*256;   const float* lb1l = lb1 + l*256;
  const float* g2l  = g2  + l*256;   const float* lb2l = lb2 + l*256;
  const u16*   wq   = wqkvf + (size_t)l*196608;
  const u16*   wo   = wof + (size_t)l*65536;
  const u16*   w1   = w1f + (size_t)l*262144;
  const u16*   w2   = w2f + (size_t)l*262144;
  const float* b1l  = b1 + l*1024;   const float* b2l  = b2 + l*256;
  const u16*   eh   = ehf + (size_t)l*65536;
  const float* ehbl = ehb + l*256;   const float* efwl = efw + l*256;
  const float  efbv = efb[l];
  const u16*   nh   = nhT + (size_t)l*65536;
  const float* nhbl = nhb + l*256;   const float* nfwl = nfw + l*256;
  const float  nfbv = nfb[l];

  const int n = blockIdx.x, t = threadIdx.x;
  const int w = t >> 6, ln = t & 63, lr = ln & 15, lg = ln >> 4;
  const int d0 = ln*4;
  const f4v zf = {0.f, 0.f, 0.f, 0.f};

  // A-operand LDS read bases (bf16 elements)
  const int a0off = lr*264      + lg*8;
  const int a1off = (16+lr)*264 + lg*8;
  const int a2off = 32*264      + lg*8;

  // ===== Phase 1: build tokens -> tok bf16 + LN1 -> xb (x)
  for(int row = w; row < 33; row += 8){
    float v0, v1, v2, v3;
    if(row == 0){
      const float4 f = *(const float4*)(emb_ndl + (size_t)species[n]*256 + d0);
      v0 = f.x; v1 = f.y; v2 = f.z; v3 = f.w;
    }else{
      const int m = row - 1;
      const size_t em = (size_t)n*32 + m;
      float4 msg = *(const float4*)(emb_nb + (size_t)nspec[em]*256 + d0);
      if(l){
        const uint2 o2 = *(const uint2*)(oe + (size_t)rni[em]*256 + d0);
        msg.x = 0.5f*(msg.x + b2f(o2.x & 0xffffu));
        msg.y = 0.5f*(msg.y + b2f(o2.x >> 16));
        msg.z = 0.5f*(msg.z + b2f(o2.y & 0xffffu));
        msg.w = 0.5f*(msg.w + b2f(o2.y >> 16));
      }
      const float e0 = evec[em*3], e1 = evec[em*3+1], e2 = evec[em*3+2], dd = edist[em];
      const float4 w0 = *(const float4*)(Wrl + d0),        w1v = *(const float4*)(Wrl + 256 + d0);
      const float4 w2v = *(const float4*)(Wrl + 512 + d0), w3  = *(const float4*)(Wrl + 768 + d0);
      const float4 bb = *(const float4*)(brl + d0);
      const float c = cutf[em];
      v0 = (msg.x + e0*w0.x + e1*w1v.x + e2*w2v.x + dd*w3.x + bb.x)*c;
      v1 = (msg.y + e0*w0.y + e1*w1v.y + e2*w2v.y + dd*w3.y + bb.y)*c;
      v2 = (msg.z + e0*w0.z + e1*w1v.z + e2*w2v.z + dd*w3.z + bb.z)*c;
      v3 = (msg.w + e0*w0.w + e1*w1v.w + e2*w2v.w + dd*w3.w + bb.w)*c;
    }
    uint2 tv; tv.x = cvtpk(v0, v1); tv.y = cvtpk(v2, v3);
    *(uint2*)(tok + row*264 + d0) = tv;
    float s1 = v0+v1+v2+v3, s2 = v0*v0+v1*v1+v2*v2+v3*v3;
#pragma unroll
    for(int off = 1; off < 64; off <<= 1){ s1 += __shfl_xor(s1, off); s2 += __shfl_xor(s2, off); }
    const float mu  = s1*(1.f/256.f);
    const float inv = rsqrtf(s2*(1.f/256.f) - mu*mu + 1e-5f);
    uint2 xo;
    xo.x = cvtpk((v0-mu)*inv*g1l[d0]   + lb1l[d0],   (v1-mu)*inv*g1l[d0+1] + lb1l[d0+1]);
    xo.y = cvtpk((v2-mu)*inv*g1l[d0+2] + lb1l[d0+2], (v3-mu)*inv*g1l[d0+3] + lb1l[d0+3]);
    *(uint2*)(xb + row*264 + d0) = xo;
  }
  __syncthreads();

  // ===== Phase 3: Q,K tiles (q: ctg 0-15 -> qb, k: 16-31 -> kb), ks-outer
  {
    f4v acc[4][3];
#pragma unroll
    for(int i = 0; i < 4; i++){ acc[i][0] = zf; acc[i][1] = zf; acc[i][2] = zf; }
#pragma unroll
    for(int ks = 0; ks < 8; ks++){
      s8v x0 = *(const s8v*)(xb + a0off + ks*32);
      s8v x1 = *(const s8v*)(xb + a1off + ks*32);
      s8v x2 = *(const s8v*)(xb + a2off + ks*32);
#pragma unroll
      for(int i = 0; i < 4; i++){
        s8v b = *(const s8v*)(wq + (size_t)(w*4 + i)*4096 + ks*512 + ln*8);
        acc[i][0] = mfma16(x0, b, acc[i][0]);
        acc[i][1] = mfma16(x1, b, acc[i][1]);
        acc[i][2] = mfma16(x2, b, acc[i][2]);
      }
    }
#pragma unroll
    for(int i = 0; i < 4; i++){
      const int ctg = w*4 + i;
#pragma unroll
      for(int rt = 0; rt < 3; rt++){
        f4v av = acc[i][rt];
#pragma unroll
        for(int r = 0; r < 4; r++){
          int row = rt*16 + lg*4 + r;
          if(row > 32) continue;
          u16 bv = f2bf(av[r]);
          if(ctg < 16) qb[row*264 + ctg*16 + lr] = bv;
          else         kb[row*264 + (ctg-16)*16 + lr] = bv;
        }
      }
    }
  }
  __syncthreads();

  // ===== Phase 4: scores + softmax, wave w = head w; P stored over q cols (in-place)
  const u32 mb = maskb[n];
  const int hb = w*32;
  u16* Pb = qb + hb;
  float* a32W = a32 + w*33;
  const bool vmask0 = (lr == 0) || ((mb >> (lr-1)) & 1u);   // cols 0..15
  const bool vmask1 = (mb >> (15+lr)) & 1u;                 // cols 16..31 -> edge 15+lr
  const bool vmask2 = (lr == 0) && ((mb >> 31) & 1u);       // col 32 -> edge 31
  {
    s8v aq[3], bk[3];
#pragma unroll
    for(int rt = 0; rt < 3; rt++){ int row = rt*16 + lr; row = row > 32 ? 32 : row; aq[rt] = *(const s8v*)(qb + row*264 + hb + lg*8); }
#pragma unroll
    for(int ct = 0; ct < 3; ct++){ int tk = ct*16 + lr; tk = tk > 32 ? 32 : tk; bk[ct] = *(const s8v*)(kb + tk*264 + hb + lg*8); }
    f4v sS[3][3];
#pragma unroll
    for(int rt = 0; rt < 3; rt++)
#pragma unroll
      for(int ct = 0; ct < 3; ct++) sS[rt][ct] = mfma16(aq[rt], bk[ct], zf);
    softmax_store(sS, Pb, a32W, vmask0, vmask1, vmask2, lg, lr);
  }
  __syncthreads();   // all K reads done before kb is overwritten with V

  // ===== Phase 5: V tiles -> kb ([33][264] layout), ks-outer, 2 per wave
  {
    f4v acc[2][3];
#pragma unroll
    for(int i = 0; i < 2; i++){ acc[i][0] = zf; acc[i][1] = zf; acc[i][2] = zf; }
#pragma unroll
    for(int ks = 0; ks < 8; ks++){
      s8v x0 = *(const s8v*)(xb + a0off + ks*32);
      s8v x1 = *(const s8v*)(xb + a1off + ks*32);
      s8v x2 = *(const s8v*)(xb + a2off + ks*32);
#pragma unroll
      for(int i = 0; i < 2; i++){
        s8v b = *(const s8v*)(wq + (size_t)(32 + w*2 + i)*4096 + ks*512 + ln*8);
        acc[i][0] = mfma16(x0, b, acc[i][0]);
        acc[i][1] = mfma16(x1, b, acc[i][1]);
        acc[i][2] = mfma16(x2, b, acc[i][2]);
      }
    }
#pragma unroll
    for(int i = 0; i < 2; i++){
      const int vt = w*2 + i;
#pragma unroll
      for(int rt = 0; rt < 3; rt++){
        f4v av = acc[i][rt];
#pragma unroll
        for(int r = 0; r < 4; r++){
          int row = rt*16 + lg*4 + r;
          if(row > 32) continue;
          kb[row*264 + vt*16 + lr] = f2bf(av[r]);
        }
      }
    }
  }
  __syncthreads();

  // ===== Phase 6: PV. ap = P (consumed to regs), o overwrites P in qb (round-5 verbatim)
  {
    s8v ap[3];
#pragma unroll
    for(int rt = 0; rt < 3; rt++){ int row = rt*16 + lr; row = row > 32 ? 32 : row; ap[rt] = *(const s8v*)(qb + row*264 + hb + lg*8); }
#pragma unroll
    for(int c2 = 0; c2 < 2; c2++){
      s8v b;
#pragma unroll
      for(int j = 0; j < 8; j++) b[j] = (short)kb[(lg*8 + j)*264 + hb + c2*16 + lr];
      const float vv = b2f(kb[32*264 + hb + c2*16 + lr]);
#pragma unroll
      for(int rt = 0; rt < 3; rt++){
        f4v o_ = mfma16(ap[rt], b, zf);
#pragma unroll
        for(int r = 0; r < 4; r++){
          int row = rt*16 + lg*4 + r;
          int rc = row > 32 ? 32 : row;
          float ov = o_[r] + a32W[rc]*vv;
          if(row < 33) qb[row*264 + hb + c2*16 + lr] = f2bf(ov);
        }
      }
    }
  }
  __syncthreads();

  // ===== Phase 7: O @ Wo + residual into tok (bf16), ks-outer, round-5 stores
  {
    f4v acc[2][3];
#pragma unroll
    for(int i = 0; i < 2; i++){ acc[i][0] = zf; acc[i][1] = zf; acc[i][2] = zf; }
#pragma unroll
    for(int ks = 0; ks < 8; ks++){
      s8v A0 = *(const s8v*)(qb + a0off + ks*32);
      s8v A1 = *(const s8v*)(qb + a1off + ks*32);
      s8v A2 = *(const s8v*)(qb + a2off + ks*32);
#pragma unroll
      for(int i = 0; i < 2; i++){
        s8v b = *(const s8v*)(wo + (size_t)(w*2 + i)*4096 + ks*512 + ln*8);
        acc[i][0] = mfma16(A0, b, acc[i][0]);
        acc[i][1] = mfma16(A1, b, acc[i][1]);
        acc[i][2] = mfma16(A2, b, acc[i][2]);
      }
    }
#pragma unroll
    for(int i = 0; i < 2; i++){
      const int col = (w*2 + i)*16 + lr;
#pragma unroll
      for(int rt = 0; rt < 3; rt++){
        f4v av = acc[i][rt];
#pragma unroll
        for(int r = 0; r < 4; r++){
          int row = rt*16 + lg*4 + r;
          if(row > 32) continue;
          float tv = b2f(tok[row*264 + col]) + av[r];
          tok[row*264 + col] = f2bf(tv);
        }
      }
    }
  }
  __syncthreads();

  // ===== Phase 8: LN2 -> xb (y)
  for(int row = w; row < 33; row += 8){
    uint2 tv2 = *(const uint2*)(tok + row*264 + d0);
    float v0 = b2f(tv2.x & 0xffffu), v1 = b2f(tv2.x >> 16);
    float v2 = b2f(tv2.y & 0xffffu), v3 = b2f(tv2.y >> 16);
    float s1 = v0+v1+v2+v3, s2 = v0*v0+v1*v1+v2*v2+v3*v3;
#pragma unroll
    for(int off = 1; off < 64; off <<= 1){ s1 += __shfl_xor(s1, off); s2 += __shfl_xor(s2, off); }
    const float mu  = s1*(1.f/256.f);
    const float inv = rsqrtf(s2*(1.f/256.f) - mu*mu + 1e-5f);
    uint2 yo;
    yo.x = cvtpk((v0-mu)*inv*g2l[d0]   + lb2l[d0],   (v1-mu)*inv*g2l[d0+1] + lb2l[d0+1]);
    yo.y = cvtpk((v2-mu)*inv*g2l[d0+2] + lb2l[d0+2], (v3-mu)*inv*g2l[d0+3] + lb2l[d0+3]);
    *(uint2*)(xb + row*264 + d0) = yo;
  }
  __syncthreads();

  // ===== Phase 9: FFN. ks-outer both halves; h chunks in qb; facc persistent
  f4v facc[2][3];
#pragma unroll
  for(int i = 0; i < 2; i++){ facc[i][0] = zf; facc[i][1] = zf; facc[i][2] = zf; }

  for(int ch = 0; ch < 4; ch++){
    {
      f4v acc[2][3];
#pragma unroll
      for(int i = 0; i < 2; i++){ acc[i][0] = zf; acc[i][1] = zf; acc[i][2] = zf; }
#pragma unroll
      for(int ks = 0; ks < 8; ks++){
        s8v y0 = *(const s8v*)(xb + a0off + ks*32);
        s8v y1 = *(const s8v*)(xb + a1off + ks*32);
        s8v y2 = *(const s8v*)(xb + a2off + ks*32);
#pragma unroll
        for(int i = 0; i < 2; i++){
          const int nt = ch*16 + w*2 + i;
          s8v b = *(const s8v*)(w1 + (size_t)nt*4096 + ks*512 + ln*8);
          acc[i][0] = mfma16(y0, b, acc[i][0]);
          acc[i][1] = mfma16(y1, b, acc[i][1]);
          acc[i][2] = mfma16(y2, b, acc[i][2]);
        }
      }
#pragma unroll
      for(int i = 0; i < 2; i++){
        const int nt = ch*16 + w*2 + i;
        const int colL = (w*2 + i)*16 + lr;
        const float bias = b1l[nt*16 + lr];
#pragma unroll
        for(int rt = 0; rt < 3; rt++){
          f4v hv = acc[i][rt];
#pragma unroll
          for(int r = 0; r < 4; r++){
            int row = rt*16 + lg*4 + r;
            if(row > 32) continue;
            float v0 = hv[r] + bias;
            qb[row*264 + colL] = f2bf(v0/(1.f + __expf(-v0)));
          }
        }
      }
    }
    __syncthreads();
#pragma unroll
    for(int ks = 0; ks < 8; ks++){
      s8v A0 = *(const s8v*)(qb + a0off + ks*32);
      s8v A1 = *(const s8v*)(qb + a1off + ks*32);
      s8v A2 = *(const s8v*)(qb + a2off + ks*32);
#pragma unroll
      for(int i = 0; i < 2; i++){
        s8v b = *(const s8v*)(w2 + (size_t)((w*2 + i)*32 + ch*8 + ks)*512 + ln*8);
        facc[i][0] = mfma16(A0, b, facc[i][0]);
        facc[i][1] = mfma16(A1, b, facc[i][1]);
        facc[i][2] = mfma16(A2, b, facc[i][2]);
      }
    }
    __syncthreads();
  }

  // ===== Phase 10: final residual -> tok; out_edge (layer 0) — round-5 verbatim
#pragma unroll
  for(int i = 0; i < 2; i++){
    const int col = (w*2 + i)*16 + lr;
    const float bias2 = b2l[col];
#pragma unroll
    for(int rt = 0; rt < 3; rt++){
#pragma unroll
      for(int r = 0; r < 4; r++){
        int row = rt*16 + lg*4 + r;
        if(row > 32) continue;
        float tv = b2f(tok[row*264 + col]) + facc[i][rt][r] + bias2;
        u16 tvb = f2bf(tv);
        tok[row*264 + col] = tvb;
        if(l == 0 && row > 0) oe[((size_t)n*32 + (row-1))*256 + col] = tvb;
      }
    }
  }
  __syncthreads();

  // ===== Phase 11: heads + energy (ks-outer edge head)
  float rp[3][4];
#pragma unroll
  for(int a = 0; a < 3; a++)
#pragma unroll
    for(int r = 0; r < 4; r++) rp[a][r] = 0.f;
  {
    f4v acc[2][3];
#pragma unroll
    for(int i = 0; i < 2; i++){ acc[i][0] = zf; acc[i][1] = zf; acc[i][2] = zf; }
#pragma unroll
    for(int ks = 0; ks < 8; ks++){
      s8v A0 = *(const s8v*)(tok + a0off + ks*32);
      s8v A1 = *(const s8v*)(tok + a1off + ks*32);
      s8v A2 = *(const s8v*)(tok + a2off + ks*32);
#pragma unroll
      for(int i = 0; i < 2; i++){
        s8v b = *(const s8v*)(eh + (size_t)(w*2 + i)*4096 + ks*512 + ln*8);
        acc[i][0] = mfma16(A0, b, acc[i][0]);
        acc[i][1] = mfma16(A1, b, acc[i][1]);
        acc[i][2] = mfma16(A2, b, acc[i][2]);
      }
    }
#pragma unroll
    for(int i = 0; i < 2; i++){
      const int col = (w*2 + i)*16 + lr;
      const float bb = ehbl[col], ff = efwl[col];
#pragma unroll
      for(int rt = 0; rt < 3; rt++)
#pragma unroll
        for(int r = 0; r < 4; r++){
          float v0 = acc[i][rt][r] + bb;
          rp[rt][r] += (v0/(1.f + __expf(-v0)))*ff;
        }
    }
  }
#pragma unroll
  for(int rt = 0; rt < 3; rt++)
#pragma unroll
    for(int r = 0; r < 4; r++){
      float v = rp[rt][r];
#pragma unroll
      for(int off = 1; off < 16; off <<= 1) v += __shfl_xor(v, off);
      if(lr == 0) ered[w*48 + rt*16 + lg*4 + r] = v;
    }

  if(w < 4){   // node head: thread t (<256) computes hidden[t] from tok row 0
    const u16* nr = nh + (size_t)t*256;
    float acc = 0.f;
#pragma unroll 4
    for(int dd = 0; dd < 256; dd += 8){
      uint4 ta = *(const uint4*)(tok + dd);
      uint4 na = *(const uint4*)(nr + dd);
      acc += dot2(ta.x, na.x) + dot2(ta.y, na.y) + dot2(ta.z, na.z) + dot2(ta.w, na.w);
    }
    float hv = acc + nhbl[t];
    hv = hv/(1.f + __expf(-hv));
    float pp = hv*nfwl[t];
#pragma unroll
    for(int off = 1; off < 64; off <<= 1) pp += __shfl_xor(pp, off);
    if(ln == 0) nred[w] = pp;
  }
  __syncthreads();

  if(w == 0){
    float ev = 0.f;
    if(ln < 32){
      const int row = ln + 1;
      float es = efbv;
#pragma unroll
      for(int ww = 0; ww < 8; ww++) es += ered[ww*48 + row];
      if((mb >> ln) & 1u) ev = es*cutf[(size_t)n*32 + ln];
    }
#pragma unroll
    for(int off = 1; off < 64; off <<= 1) ev += __shfl_xor(ev, off);
    if(ln == 0){
      float tot = ev + nred[0] + nred[1] + nred[2] + nred[3] + nfbv;
      energies[n] = (l ? energies[n] : 0.f) + tot;
    }
  }
}

// ---------------------------------------------------------------------------
extern "C" void kernel_launch(void* const* d_in, const int* in_sizes, int n_in,
                              void* d_out, int out_size, void* d_ws, size_t ws_size,
                              hipStream_t stream){
  (void)in_sizes; (void)n_in; (void)out_size;
  const int*   species = (const int*)d_in[0];
  const int*   nspec   = (const int*)d_in[1];
  const float* evec    = (const float*)d_in[2];
  const float* edist   = (const float*)d_in[3];
  const int*   rni     = (const int*)d_in[5];
  const float* cutf    = (const float*)d_in[6];
  const float* emb_nb  = (const float*)d_in[7];
  const float* emb_nd  = (const float*)d_in[8];
  const float* Wr      = (const float*)d_in[9];
  const float* br      = (const float*)d_in[10];
  const float* Wq      = (const float*)d_in[11];
  const float* Wk      = (const float*)d_in[12];
  const float* Wv      = (const float*)d_in[13];
  const float* Wo      = (const float*)d_in[14];
  const float* W1      = (const float*)d_in[15];
  const float* b1      = (const float*)d_in[16];
  const float* W2      = (const float*)d_in[17];
  const float* b2      = (const float*)d_in[18];
  const float* g1      = (const float*)d_in[19];
  const float* lb1     = (const float*)d_in[20];
  const float* g2      = (const float*)d_in[21];
  const float* lb2     = (const float*)d_in[22];
  const float* nhW     = (const float*)d_in[23];
  const float* nhb     = (const float*)d_in[24];
  const float* nfw     = (const float*)d_in[25];
  const float* nfb     = (const float*)d_in[26];
  const float* ehW     = (const float*)d_in[27];
  const float* ehb     = (const float*)d_in[28];
  const float* efw     = (const float*)d_in[29];
  const float* efb     = (const float*)d_in[30];
  float* energies = (float*)d_out;

  // workspace layout (total 137,920,512 B)
  char* wsb = (char*)d_ws;
  u16* oe     = (u16*)(wsb);                      // 134,217,728 B
  u16* wqkvf  = (u16*)(wsb + 134217728LL);        // 786,432 B
  u16* wof    = (u16*)(wsb + 135004160LL);        // 262,144 B
  u16* w1f    = (u16*)(wsb + 135266304LL);        // 1,048,576 B
  u16* w2f    = (u16*)(wsb + 136314880LL);        // 1,048,576 B
  u16* ehf    = (u16*)(wsb + 137363456LL);        // 262,144 B
  u16* nhT    = (u16*)(wsb + 137625600LL);        // 262,144 B
  u32* maskb  = (u32*)(wsb + 137887744LL);        // 32,768 B
  if(ws_size < 137920512ULL) return;   // undersized ws -> clean absmax failure, not a fault

  for(int l = 0; l < 2; l++){
    const size_t wqo = (size_t)l*196608;
    prep_frag<<<128, 64, 0, stream>>>(Wq + (size_t)l*65536, 8, 256, wqkvf + wqo);
    prep_frag<<<128, 64, 0, stream>>>(Wk + (size_t)l*65536, 8, 256, wqkvf + wqo + 65536);
    prep_frag<<<128, 64, 0, stream>>>(Wv + (size_t)l*65536, 8, 256, wqkvf + wqo + 131072);
    prep_frag<<<128, 64, 0, stream>>>(Wo + (size_t)l*65536, 8, 256, wof + (size_t)l*65536);
    prep_frag<<<512, 64, 0, stream>>>(W1 + (size_t)l*262144, 8, 1024, w1f + (size_t)l*262144);
    prep_frag<<<512, 64, 0, stream>>>(W2 + (size_t)l*262144, 32, 256, w2f + (size_t)l*262144);
    prep_frag<<<128, 64, 0, stream>>>(ehW + (size_t)l*65536, 8, 256, ehf + (size_t)l*65536);
    prep_plainT<<<256, 256, 0, stream>>>(nhW + (size_t)l*65536, nhT + (size_t)l*65536);
  }
  prep_mask<<<32, 256, 0, stream>>>((const unsigned char*)d_in[4], maskb);

  for(int l = 0; l < 2; l++){
    k_layer<<<8192, 512, 0, stream>>>(species, nspec, evec, edist, cutf, rni,
        emb_nb, emb_nd, Wr, br, g1, lb1, g2, lb2,
        wqkvf, wof, w1f, w2f, b1, b2,
        ehf, ehb, efw, efb, nhT, nhb, nfw, nfb,
        maskb, oe, l, energies);
  }
}

// Round 10
// 1966.186 us; speedup vs baseline: 3.1174x; 1.0342x over previous
//
#include <hip/hip_runtime.h>

typedef unsigned int u32;
typedef unsigned short u16;
typedef __attribute__((ext_vector_type(8))) short s8v;   // 8 x bf16 (4 VGPRs)
typedef __attribute__((ext_vector_type(4))) float f4v;   // MFMA accumulator

#define DEV static __device__ __forceinline__

DEV float b2f(u32 u){ return __uint_as_float(u << 16); }
DEV u16 f2bf(float f){ u32 u = __float_as_uint(f); u += 0x7fffu + ((u >> 16) & 1u); return (u16)(u >> 16); }
DEV u32 cvtpk(float lo, float hi){ u32 r; asm("v_cvt_pk_bf16_f32 %0, %1, %2" : "=v"(r) : "v"(lo), "v"(hi)); return r; }
DEV float vrcp(float x){ float r; asm("v_rcp_f32 %0, %1" : "=v"(r) : "v"(x)); return r; }
DEV float fsilu(float v){ return v*vrcp(1.f + __expf(-v)); }
DEV float dot2(u32 a, u32 b){ return b2f(a & 0xffffu)*b2f(b & 0xffffu) + b2f(a >> 16)*b2f(b >> 16); }
DEV f4v mfma16(s8v a, s8v b, f4v c){ return __builtin_amdgcn_mfma_f32_16x16x32_bf16(a, b, c, 0, 0, 0); }

// ---------------------------------------------------------------------------
// Weight prep: f32 [K][N] -> bf16 MFMA-frag blocks.
// Block b = nt*Ksteps+ks holds 512 bf16: lane ln, elem j <-> W[ks*32+8*(ln>>4)+j][nt*16+(ln&15)]
// ---------------------------------------------------------------------------
__global__ void prep_frag(const float* __restrict__ src, const int Ksteps, const int Nout,
                          u16* __restrict__ dst){
  const int b = blockIdx.x;
  const int ks = b % Ksteps, nt = b / Ksteps;
  const int ln = threadIdx.x;
  const int col = nt*16 + (ln & 15);
  const int kr  = ks*32 + (ln >> 4)*8;
  __align__(16) u16 tmp[8];
#pragma unroll
  for(int j = 0; j < 8; j++) tmp[j] = f2bf(src[(size_t)(kr + j)*Nout + col]);
  *(uint4*)(dst + (size_t)b*512 + ln*8) = *(const uint4*)tmp;
}

// plain transpose for node-head: dst[j][d] = src[d][j], 256x256
__global__ void prep_plainT(const float* __restrict__ src, u16* __restrict__ dst){
  const int j = blockIdx.x, d = threadIdx.x;
  dst[(size_t)j*256 + d] = f2bf(src[(size_t)d*256 + j]);
}

// padding_mask -> bitmask per node, runtime dtype detection (bool8/int32/f32)
__global__ void prep_mask(const unsigned char* __restrict__ pm, u32* __restrict__ mb){
  __shared__ int s0, s3;
  if(threadIdx.x == 0){ s0 = 0; s3 = 0; }
  __syncthreads();
  int a0 = 0, a3 = 0;
  for(int i = threadIdx.x; i < 4096; i += 256){
    unsigned char v = pm[i];
    if(v){ int r = i & 3; if(r == 0) a0 = 1; if(r == 3) a3 = 1; }
  }
  if(a0) s0 = 1;
  if(a3) s3 = 1;
  __syncthreads();
  int mode;                       // 0 = bool8, 1 = int32, 2 = float32
  if(s0 && !s3) mode = 1; else if(!s0 && s3) mode = 2; else mode = 0;
  const int n = blockIdx.x*256 + threadIdx.x;
  u32 bits = 0;
  for(int m = 0; m < 32; m++){
    size_t idx = (size_t)n*32 + m;
    bool v;
    if(mode == 0)      v = pm[idx] != 0;
    else if(mode == 1) v = ((const int*)pm)[idx] != 0;
    else               v = ((const float*)pm)[idx] != 0.f;
    bits |= (v ? 1u : 0u) << m;
  }
  mb[n] = bits;
}

// masked softmax over D-layout scores; stores P (bf16) in-place over q columns
// (stride 264) + col-32 fixup (f32)
DEV void softmax_store(const f4v sS[3][3], u16* Pb, float* a32W,
                       const bool vmask0, const bool vmask1, const bool vmask2,
                       const int lg, const int lr){
  const float sc = 0.17677669529663687f;  // 1/sqrt(32)
#pragma unroll
  for(int rt = 0; rt < 3; rt++){
#pragma unroll
    for(int r = 0; r < 4; r++){
      float sv0 = vmask0 ? sS[rt][0][r]*sc : -1e9f;
      float sv1 = vmask1 ? sS[rt][1][r]*sc : -1e9f;
      float sv2 = vmask2 ? sS[rt][2][r]*sc : -1e9f;
      float m_ = fmaxf(fmaxf(sv0, sv1), sv2);
#pragma unroll
      for(int off = 1; off < 16; off <<= 1) m_ = fmaxf(m_, __shfl_xor(m_, off));
      float e0 = __expf(sv0 - m_), e1 = __expf(sv1 - m_), e2 = __expf(sv2 - m_);
      float sum = e0 + e1 + e2;
#pragma unroll
      for(int off = 1; off < 16; off <<= 1) sum += __shfl_xor(sum, off);
      const float rinv = 1.f/sum;
      const int row = rt*16 + lg*4 + r;
      if(row < 33){
        Pb[row*264 + lr]      = f2bf(e0*rinv);
        Pb[row*264 + 16 + lr] = f2bf(e1*rinv);
        if(lr == 0) a32W[row] = e2*rinv;
      }
    }
  }
}

// ---------------------------------------------------------------------------
// Fused per-layer kernel. block = node (8192), 512 threads = 8 waves, wave = head.
// LDS 73,296 B: tok[33][264] | qb (q/P/o/h) | kb (k/v) | xb (x/y)
//             | a32 8x[33] (aliased by ered post-attention) | nred | nhp[512]
// GEMM phases ks-outer; stores per-element guarded (round-8 structure).
// ---------------------------------------------------------------------------
__global__ __launch_bounds__(512, 4) void k_layer(
    const int* __restrict__ species, const int* __restrict__ nspec,
    const float* __restrict__ evec, const float* __restrict__ edist,
    const float* __restrict__ cutf, const int* __restrict__ rni,
    const float* __restrict__ emb_nb, const float* __restrict__ emb_nd,
    const float* __restrict__ Wr, const float* __restrict__ br,
    const float* __restrict__ g1, const float* __restrict__ lb1,
    const float* __restrict__ g2, const float* __restrict__ lb2,
    const u16* __restrict__ wqkvf, const u16* __restrict__ wof,
    const u16* __restrict__ w1f, const u16* __restrict__ w2f,
    const float* __restrict__ b1, const float* __restrict__ b2,
    const u16* __restrict__ ehf, const float* __restrict__ ehb,
    const float* __restrict__ efw, const float* __restrict__ efb,
    const u16* __restrict__ nhT, const float* __restrict__ nhb,
    const float* __restrict__ nfw, const float* __restrict__ nfb,
    const u32* __restrict__ maskb, u16* __restrict__ oe,
    const int layer, float* __restrict__ energies)
{
  __shared__ __align__(16) unsigned char sm[73296];
  u16* tok    = (u16*)sm;             // [33][264] bf16 residual stream
  u16* qb     = (u16*)(sm + 17424);   // q -> P -> o -> h
  u16* kb     = (u16*)(sm + 34848);   // k -> v
  u16* xb     = (u16*)(sm + 52272);   // x -> y
  float* a32  = (float*)(sm + 69696); // 8 x 33 f32
  float* ered = (float*)(sm + 69696); // alias a32 (a32 dead after PV)
  float* nred = (float*)(sm + 71232); // 4 f32
  float* nhp  = (float*)(sm + 71248); // 512 f32 node-head partials

  const int l = layer;
  const float* emb_ndl = emb_nd + (size_t)l*30464;
  const float* Wrl  = Wr  + l*1024;  const float* brl  = br  + l*256;
  const float* g1l  = g1  + l*256;   const float* lb1l = lb1 + l*256;
  const float* g2l  = g2  + l*256;   const float* lb2l = lb2 + l*256;
  const u16*   wq   = wqkvf + (size_t)l*196608;
  const u16*   wo   = wof + (size_t)l*65536;
  const u16*   w1   = w1f + (size_t)l*262144;
  const u16*   w2   = w2f + (size_t)l*262144;
  const float* b1l  = b1 + l*1024;   const float* b2l  = b2 + l*256;
  const u16*   eh   = ehf + (size_t)l*65536;
  const float* ehbl = ehb + l*256;   const float* efwl = efw + l*256;
  const float  efbv = efb[l];
  const u16*   nh   = nhT + (size_t)l*65536;
  const float* nhbl = nhb + l*256;   const float* nfwl = nfw + l*256;
  const float  nfbv = nfb[l];

  const int n = blockIdx.x, t = threadIdx.x;
  const int w = t >> 6, ln = t & 63, lr = ln & 15, lg = ln >> 4;
  const int d0 = ln*4;
  const f4v zf = {0.f, 0.f, 0.f, 0.f};

  // A-operand LDS read bases (bf16 elements)
  const int a0off = lr*264      + lg*8;
  const int a1off = (16+lr)*264 + lg*8;
  const int a2off = 32*264      + lg*8;

  // ===== Phase 1: build tokens -> tok bf16 + LN1 -> xb (x)
  for(int row = w; row < 33; row += 8){
    float v0, v1, v2, v3;
    if(row == 0){
      const float4 f = *(const float4*)(emb_ndl + (size_t)species[n]*256 + d0);
      v0 = f.x; v1 = f.y; v2 = f.z; v3 = f.w;
    }else{
      const int m = row - 1;
      const size_t em = (size_t)n*32 + m;
      float4 msg = *(const float4*)(emb_nb + (size_t)nspec[em]*256 + d0);
      if(l){
        const uint2 o2 = *(const uint2*)(oe + (size_t)rni[em]*256 + d0);
        msg.x = 0.5f*(msg.x + b2f(o2.x & 0xffffu));
        msg.y = 0.5f*(msg.y + b2f(o2.x >> 16));
        msg.z = 0.5f*(msg.z + b2f(o2.y & 0xffffu));
        msg.w = 0.5f*(msg.w + b2f(o2.y >> 16));
      }
      const float e0 = evec[em*3], e1 = evec[em*3+1], e2 = evec[em*3+2], dd = edist[em];
      const float4 w0 = *(const float4*)(Wrl + d0),        w1v = *(const float4*)(Wrl + 256 + d0);
      const float4 w2v = *(const float4*)(Wrl + 512 + d0), w3  = *(const float4*)(Wrl + 768 + d0);
      const float4 bb = *(const float4*)(brl + d0);
      const float c = cutf[em];
      v0 = (msg.x + e0*w0.x + e1*w1v.x + e2*w2v.x + dd*w3.x + bb.x)*c;
      v1 = (msg.y + e0*w0.y + e1*w1v.y + e2*w2v.y + dd*w3.y + bb.y)*c;
      v2 = (msg.z + e0*w0.z + e1*w1v.z + e2*w2v.z + dd*w3.z + bb.z)*c;
      v3 = (msg.w + e0*w0.w + e1*w1v.w + e2*w2v.w + dd*w3.w + bb.w)*c;
    }
    uint2 tv; tv.x = cvtpk(v0, v1); tv.y = cvtpk(v2, v3);
    *(uint2*)(tok + row*264 + d0) = tv;
    float s1 = v0+v1+v2+v3, s2 = v0*v0+v1*v1+v2*v2+v3*v3;
#pragma unroll
    for(int off = 1; off < 64; off <<= 1){ s1 += __shfl_xor(s1, off); s2 += __shfl_xor(s2, off); }
    const float mu  = s1*(1.f/256.f);
    const float inv = rsqrtf(s2*(1.f/256.f) - mu*mu + 1e-5f);
    uint2 xo;
    xo.x = cvtpk((v0-mu)*inv*g1l[d0]   + lb1l[d0],   (v1-mu)*inv*g1l[d0+1] + lb1l[d0+1]);
    xo.y = cvtpk((v2-mu)*inv*g1l[d0+2] + lb1l[d0+2], (v3-mu)*inv*g1l[d0+3] + lb1l[d0+3]);
    *(uint2*)(xb + row*264 + d0) = xo;
  }
  __syncthreads();

  // ===== Phase 3: Q,K tiles (q: ctg 0-15 -> qb, k: 16-31 -> kb), ks-outer
  {
    f4v acc[4][3];
#pragma unroll
    for(int i = 0; i < 4; i++){ acc[i][0] = zf; acc[i][1] = zf; acc[i][2] = zf; }
#pragma unroll
    for(int ks = 0; ks < 8; ks++){
      s8v x0 = *(const s8v*)(xb + a0off + ks*32);
      s8v x1 = *(const s8v*)(xb + a1off + ks*32);
      s8v x2 = *(const s8v*)(xb + a2off + ks*32);
#pragma unroll
      for(int i = 0; i < 4; i++){
        s8v b = *(const s8v*)(wq + (size_t)(w*4 + i)*4096 + ks*512 + ln*8);
        acc[i][0] = mfma16(x0, b, acc[i][0]);
        acc[i][1] = mfma16(x1, b, acc[i][1]);
        acc[i][2] = mfma16(x2, b, acc[i][2]);
      }
    }
#pragma unroll
    for(int i = 0; i < 4; i++){
      const int ctg = w*4 + i;
#pragma unroll
      for(int rt = 0; rt < 3; rt++){
        f4v av = acc[i][rt];
#pragma unroll
        for(int r = 0; r < 4; r++){
          int row = rt*16 + lg*4 + r;
          if(row > 32) continue;
          u16 bv = f2bf(av[r]);
          if(ctg < 16) qb[row*264 + ctg*16 + lr] = bv;
          else         kb[row*264 + (ctg-16)*16 + lr] = bv;
        }
      }
    }
  }
  __syncthreads();

  // ===== Phase 4: scores + softmax, wave w = head w; P stored over q cols (in-place)
  const u32 mb = maskb[n];
  const int hb = w*32;
  u16* Pb = qb + hb;
  float* a32W = a32 + w*33;
  const bool vmask0 = (lr == 0) || ((mb >> (lr-1)) & 1u);   // cols 0..15
  const bool vmask1 = (mb >> (15+lr)) & 1u;                 // cols 16..31 -> edge 15+lr
  const bool vmask2 = (lr == 0) && ((mb >> 31) & 1u);       // col 32 -> edge 31
  {
    s8v aq[3], bk[3];
#pragma unroll
    for(int rt = 0; rt < 3; rt++){ int row = rt*16 + lr; row = row > 32 ? 32 : row; aq[rt] = *(const s8v*)(qb + row*264 + hb + lg*8); }
#pragma unroll
    for(int ct = 0; ct < 3; ct++){ int tk = ct*16 + lr; tk = tk > 32 ? 32 : tk; bk[ct] = *(const s8v*)(kb + tk*264 + hb + lg*8); }
    f4v sS[3][3];
#pragma unroll
    for(int rt = 0; rt < 3; rt++)
#pragma unroll
      for(int ct = 0; ct < 3; ct++) sS[rt][ct] = mfma16(aq[rt], bk[ct], zf);
    softmax_store(sS, Pb, a32W, vmask0, vmask1, vmask2, lg, lr);
  }
  __syncthreads();   // all K reads done before kb is overwritten with V

  // ===== Phase 5: V tiles -> kb ([33][264] layout), ks-outer, 2 per wave
  {
    f4v acc[2][3];
#pragma unroll
    for(int i = 0; i < 2; i++){ acc[i][0] = zf; acc[i][1] = zf; acc[i][2] = zf; }
#pragma unroll
    for(int ks = 0; ks < 8; ks++){
      s8v x0 = *(const s8v*)(xb + a0off + ks*32);
      s8v x1 = *(const s8v*)(xb + a1off + ks*32);
      s8v x2 = *(const s8v*)(xb + a2off + ks*32);
#pragma unroll
      for(int i = 0; i < 2; i++){
        s8v b = *(const s8v*)(wq + (size_t)(32 + w*2 + i)*4096 + ks*512 + ln*8);
        acc[i][0] = mfma16(x0, b, acc[i][0]);
        acc[i][1] = mfma16(x1, b, acc[i][1]);
        acc[i][2] = mfma16(x2, b, acc[i][2]);
      }
    }
#pragma unroll
    for(int i = 0; i < 2; i++){
      const int vt = w*2 + i;
#pragma unroll
      for(int rt = 0; rt < 3; rt++){
        f4v av = acc[i][rt];
#pragma unroll
        for(int r = 0; r < 4; r++){
          int row = rt*16 + lg*4 + r;
          if(row > 32) continue;
          kb[row*264 + vt*16 + lr] = f2bf(av[r]);
        }
      }
    }
  }
  __syncthreads();

  // ===== Phase 6: PV. ap = P (consumed to regs), o overwrites P in qb
  {
    s8v ap[3];
#pragma unroll
    for(int rt = 0; rt < 3; rt++){ int row = rt*16 + lr; row = row > 32 ? 32 : row; ap[rt] = *(const s8v*)(qb + row*264 + hb + lg*8); }
#pragma unroll
    for(int c2 = 0; c2 < 2; c2++){
      s8v b;
#pragma unroll
      for(int j = 0; j < 8; j++) b[j] = (short)kb[(lg*8 + j)*264 + hb + c2*16 + lr];
      const float vv = b2f(kb[32*264 + hb + c2*16 + lr]);
#pragma unroll
      for(int rt = 0; rt < 3; rt++){
        f4v o_ = mfma16(ap[rt], b, zf);
#pragma unroll
        for(int r = 0; r < 4; r++){
          int row = rt*16 + lg*4 + r;
          int rc = row > 32 ? 32 : row;
          float ov = o_[r] + a32W[rc]*vv;
          if(row < 33) qb[row*264 + hb + c2*16 + lr] = f2bf(ov);
        }
      }
    }
  }
  __syncthreads();

  // ===== Phase 7: O @ Wo + residual into tok (bf16), ks-outer
  {
    f4v acc[2][3];
#pragma unroll
    for(int i = 0; i < 2; i++){ acc[i][0] = zf; acc[i][1] = zf; acc[i][2] = zf; }
#pragma unroll
    for(int ks = 0; ks < 8; ks++){
      s8v A0 = *(const s8v*)(qb + a0off + ks*32);
      s8v A1 = *(const s8v*)(qb + a1off + ks*32);
      s8v A2 = *(const s8v*)(qb + a2off + ks*32);
#pragma unroll
      for(int i = 0; i < 2; i++){
        s8v b = *(const s8v*)(wo + (size_t)(w*2 + i)*4096 + ks*512 + ln*8);
        acc[i][0] = mfma16(A0, b, acc[i][0]);
        acc[i][1] = mfma16(A1, b, acc[i][1]);
        acc[i][2] = mfma16(A2, b, acc[i][2]);
      }
    }
#pragma unroll
    for(int i = 0; i < 2; i++){
      const int col = (w*2 + i)*16 + lr;
#pragma unroll
      for(int rt = 0; rt < 3; rt++){
        f4v av = acc[i][rt];
#pragma unroll
        for(int r = 0; r < 4; r++){
          int row = rt*16 + lg*4 + r;
          if(row > 32) continue;
          float tv = b2f(tok[row*264 + col]) + av[r];
          tok[row*264 + col] = f2bf(tv);
        }
      }
    }
  }
  __syncthreads();

  // ===== Phase 8: LN2 -> xb (y)
  for(int row = w; row < 33; row += 8){
    uint2 tv2 = *(const uint2*)(tok + row*264 + d0);
    float v0 = b2f(tv2.x & 0xffffu), v1 = b2f(tv2.x >> 16);
    float v2 = b2f(tv2.y & 0xffffu), v3 = b2f(tv2.y >> 16);
    float s1 = v0+v1+v2+v3, s2 = v0*v0+v1*v1+v2*v2+v3*v3;
#pragma unroll
    for(int off = 1; off < 64; off <<= 1){ s1 += __shfl_xor(s1, off); s2 += __shfl_xor(s2, off); }
    const float mu  = s1*(1.f/256.f);
    const float inv = rsqrtf(s2*(1.f/256.f) - mu*mu + 1e-5f);
    uint2 yo;
    yo.x = cvtpk((v0-mu)*inv*g2l[d0]   + lb2l[d0],   (v1-mu)*inv*g2l[d0+1] + lb2l[d0+1]);
    yo.y = cvtpk((v2-mu)*inv*g2l[d0+2] + lb2l[d0+2], (v3-mu)*inv*g2l[d0+3] + lb2l[d0+3]);
    *(uint2*)(xb + row*264 + d0) = yo;
  }
  __syncthreads();

  // ===== Phase 9: FFN. ks-outer both halves; h chunks in qb; facc persistent
  f4v facc[2][3];
#pragma unroll
  for(int i = 0; i < 2; i++){ facc[i][0] = zf; facc[i][1] = zf; facc[i][2] = zf; }

  for(int ch = 0; ch < 4; ch++){
    {
      f4v acc[2][3];
#pragma unroll
      for(int i = 0; i < 2; i++){ acc[i][0] = zf; acc[i][1] = zf; acc[i][2] = zf; }
#pragma unroll
      for(int ks = 0; ks < 8; ks++){
        s8v y0 = *(const s8v*)(xb + a0off + ks*32);
        s8v y1 = *(const s8v*)(xb + a1off + ks*32);
        s8v y2 = *(const s8v*)(xb + a2off + ks*32);
#pragma unroll
        for(int i = 0; i < 2; i++){
          const int nt = ch*16 + w*2 + i;
          s8v b = *(const s8v*)(w1 + (size_t)nt*4096 + ks*512 + ln*8);
          acc[i][0] = mfma16(y0, b, acc[i][0]);
          acc[i][1] = mfma16(y1, b, acc[i][1]);
          acc[i][2] = mfma16(y2, b, acc[i][2]);
        }
      }
#pragma unroll
      for(int i = 0; i < 2; i++){
        const int nt = ch*16 + w*2 + i;
        const int colL = (w*2 + i)*16 + lr;
        const float bias = b1l[nt*16 + lr];
#pragma unroll
        for(int rt = 0; rt < 3; rt++){
          f4v hv = acc[i][rt];
#pragma unroll
          for(int r = 0; r < 4; r++){
            int row = rt*16 + lg*4 + r;
            if(row > 32) continue;
            qb[row*264 + colL] = f2bf(fsilu(hv[r] + bias));
          }
        }
      }
    }
    __syncthreads();
#pragma unroll
    for(int ks = 0; ks < 8; ks++){
      s8v A0 = *(const s8v*)(qb + a0off + ks*32);
      s8v A1 = *(const s8v*)(qb + a1off + ks*32);
      s8v A2 = *(const s8v*)(qb + a2off + ks*32);
#pragma unroll
      for(int i = 0; i < 2; i++){
        s8v b = *(const s8v*)(w2 + (size_t)((w*2 + i)*32 + ch*8 + ks)*512 + ln*8);
        facc[i][0] = mfma16(A0, b, facc[i][0]);
        facc[i][1] = mfma16(A1, b, facc[i][1]);
        facc[i][2] = mfma16(A2, b, facc[i][2]);
      }
    }
    __syncthreads();
  }

  // ===== Phase 10: final residual -> tok; out_edge (layer 0)
#pragma unroll
  for(int i = 0; i < 2; i++){
    const int col = (w*2 + i)*16 + lr;
    const float bias2 = b2l[col];
#pragma unroll
    for(int rt = 0; rt < 3; rt++){
#pragma unroll
      for(int r = 0; r < 4; r++){
        int row = rt*16 + lg*4 + r;
        if(row > 32) continue;
        float tv = b2f(tok[row*264 + col]) + facc[i][rt][r] + bias2;
        u16 tvb = f2bf(tv);
        tok[row*264 + col] = tvb;
        if(l == 0 && row > 0) oe[((size_t)n*32 + (row-1))*256 + col] = tvb;
      }
    }
  }
  __syncthreads();

  // ===== Phase 11: heads + energy
  float rp[3][4];
#pragma unroll
  for(int a = 0; a < 3; a++)
#pragma unroll
    for(int r = 0; r < 4; r++) rp[a][r] = 0.f;
  {
    f4v acc[2][3];
#pragma unroll
    for(int i = 0; i < 2; i++){ acc[i][0] = zf; acc[i][1] = zf; acc[i][2] = zf; }
#pragma unroll
    for(int ks = 0; ks < 8; ks++){
      s8v A0 = *(const s8v*)(tok + a0off + ks*32);
      s8v A1 = *(const s8v*)(tok + a1off + ks*32);
      s8v A2 = *(const s8v*)(tok + a2off + ks*32);
#pragma unroll
      for(int i = 0; i < 2; i++){
        s8v b = *(const s8v*)(eh + (size_t)(w*2 + i)*4096 + ks*512 + ln*8);
        acc[i][0] = mfma16(A0, b, acc[i][0]);
        acc[i][1] = mfma16(A1, b, acc[i][1]);
        acc[i][2] = mfma16(A2, b, acc[i][2]);
      }
    }
#pragma unroll
    for(int i = 0; i < 2; i++){
      const int col = (w*2 + i)*16 + lr;
      const float bb = ehbl[col], ff = efwl[col];
#pragma unroll
      for(int rt = 0; rt < 3; rt++)
#pragma unroll
        for(int r = 0; r < 4; r++){
          rp[rt][r] += fsilu(acc[i][rt][r] + bb)*ff;
        }
    }
  }
#pragma unroll
  for(int rt = 0; rt < 3; rt++)
#pragma unroll
    for(int r = 0; r < 4; r++){
      float v = rp[rt][r];
#pragma unroll
      for(int off = 1; off < 16; off <<= 1) v += __shfl_xor(v, off);
      if(lr == 0) ered[w*48 + rt*16 + lg*4 + r] = v;
    }

  {   // node head part A: all 512 threads; thread (j = t&255, half = t>>8)
    const int j = t & 255, half = t >> 8;
    const u16* nr = nh + (size_t)j*256 + half*128;
    const u16* tr = tok + half*128;
    float acc = 0.f;
#pragma unroll 4
    for(int dd = 0; dd < 128; dd += 8){
      uint4 ta = *(const uint4*)(tr + dd);
      uint4 na = *(const uint4*)(nr + dd);
      acc += dot2(ta.x, na.x) + dot2(ta.y, na.y) + dot2(ta.z, na.z) + dot2(ta.w, na.w);
    }
    nhp[t] = acc;
  }
  __syncthreads();

  if(t < 256){   // node head part B
    float hv = nhp[t] + nhp[t + 256] + nhbl[t];
    float pp = fsilu(hv)*nfwl[t];
#pragma unroll
    for(int off = 1; off < 64; off <<= 1) pp += __shfl_xor(pp, off);
    if(ln == 0) nred[w] = pp;
  }
  __syncthreads();

  if(w == 0){
    float ev = 0.f;
    if(ln < 32){
      const int row = ln + 1;
      float es = efbv;
#pragma unroll
      for(int ww = 0; ww < 8; ww++) es += ered[ww*48 + row];
      if((mb >> ln) & 1u) ev = es*cutf[(size_t)n*32 + ln];
    }
#pragma unroll
    for(int off = 1; off < 64; off <<= 1) ev += __shfl_xor(ev, off);
    if(ln == 0){
      float tot = ev + nred[0] + nred[1] + nred[2] + nred[3] + nfbv;
      energies[n] = (l ? energies[n] : 0.f) + tot;
    }
  }
}

// ---------------------------------------------------------------------------
extern "C" void kernel_launch(void* const* d_in, const int* in_sizes, int n_in,
                              void* d_out, int out_size, void* d_ws, size_t ws_size,
                              hipStream_t stream){
  (void)in_sizes; (void)n_in; (void)out_size;
  const int*   species = (const int*)d_in[0];
  const int*   nspec   = (const int*)d_in[1];
  const float* evec    = (const float*)d_in[2];
  const float* edist   = (const float*)d_in[3];
  const int*   rni     = (const int*)d_in[5];
  const float* cutf    = (const float*)d_in[6];
  const float* emb_nb  = (const float*)d_in[7];
  const float* emb_nd  = (const float*)d_in[8];
  const float* Wr      = (const float*)d_in[9];
  const float* br      = (const float*)d_in[10];
  const float* Wq      = (const float*)d_in[11];
  const float* Wk      = (const float*)d_in[12];
  const float* Wv      = (const float*)d_in[13];
  const float* Wo      = (const float*)d_in[14];
  const float* W1      = (const float*)d_in[15];
  const float* b1      = (const float*)d_in[16];
  const float* W2      = (const float*)d_in[17];
  const float* b2      = (const float*)d_in[18];
  const float* g1      = (const float*)d_in[19];
  const float* lb1     = (const float*)d_in[20];
  const float* g2      = (const float*)d_in[21];
  const float* lb2     = (const float*)d_in[22];
  const float* nhW     = (const float*)d_in[23];
  const float* nhb     = (const float*)d_in[24];
  const float* nfw     = (const float*)d_in[25];
  const float* nfb     = (const float*)d_in[26];
  const float* ehW     = (const float*)d_in[27];
  const float* ehb     = (const float*)d_in[28];
  const float* efw     = (const float*)d_in[29];
  const float* efb     = (const float*)d_in[30];
  float* energies = (float*)d_out;

  // workspace layout (total 137,920,512 B)
  char* wsb = (char*)d_ws;
  u16* oe     = (u16*)(wsb);                      // 134,217,728 B
  u16* wqkvf  = (u16*)(wsb + 134217728LL);        // 786,432 B
  u16* wof    = (u16*)(wsb + 135004160LL);        // 262,144 B
  u16* w1f    = (u16*)(wsb + 135266304LL);        // 1,048,576 B
  u16* w2f    = (u16*)(wsb + 136314880LL);        // 1,048,576 B
  u16* ehf    = (u16*)(wsb + 137363456LL);        // 262,144 B
  u16* nhT    = (u16*)(wsb + 137625600LL);        // 262,144 B
  u32* maskb  = (u32*)(wsb + 137887744LL);        // 32,768 B
  if(ws_size < 137920512ULL) return;   // undersized ws -> clean absmax failure, not a fault

  for(int l = 0; l < 2; l++){
    const size_t wqo = (size_t)l*196608;
    prep_frag<<<128, 64, 0, stream>>>(Wq + (size_t)l*65536, 8, 256, wqkvf + wqo);
    prep_frag<<<128, 64, 0, stream>>>(Wk + (size_t)l*65536, 8, 256, wqkvf + wqo + 65536);
    prep_frag<<<128, 64, 0, stream>>>(Wv + (size_t)l*65536, 8, 256, wqkvf + wqo + 131072);
    prep_frag<<<128, 64, 0, stream>>>(Wo + (size_t)l*65536, 8, 256, wof + (size_t)l*65536);
    prep_frag<<<512, 64, 0, stream>>>(W1 + (size_t)l*262144, 8, 1024, w1f + (size_t)l*262144);
    prep_frag<<<512, 64, 0, stream>>>(W2 + (size_t)l*262144, 32, 256, w2f + (size_t)l*262144);
    prep_frag<<<128, 64, 0, stream>>>(ehW + (size_t)l*65536, 8, 256, ehf + (size_t)l*65536);
    prep_plainT<<<256, 256, 0, stream>>>(nhW + (size_t)l*65536, nhT + (size_t)l*65536);
  }
  prep_mask<<<32, 256, 0, stream>>>((const unsigned char*)d_in[4], maskb);

  for(int l = 0; l < 2; l++){
    k_layer<<<8192, 512, 0, stream>>>(species, nspec, evec, edist, cutf, rni,
        emb_nb, emb_nd, Wr, br, g1, lb1, g2, lb2,
        wqkvf, wof, w1f, w2f, b1, b2,
        ehf, ehb, efw, efb, nhT, nhb, nfw, nfb,
        maskb, oe, l, energies);
  }
}